// Round 2
// baseline (5405.215 us; speedup 1.0000x reference)
//
#include <hip/hip_runtime.h>
#include <math.h>

#define H 256
#define L 32
#define HEADS 4
#define DH 64
#define FEAT 7
#define RB 16
#define RBC 8
#define LN_EPS 1e-5f

__device__ __forceinline__ float wave_reduce_sum64(float v) {
#pragma unroll
  for (int m = 32; m >= 1; m >>= 1) v += __shfl_xor(v, m, 64);
  return v;
}

// ---------------- encoder: enc = relu(cf@w1+b1)@w2+b2 ; q = (enc@wq+bq)/8 ; p[h,c] = sum_d q[h,d]*wk[c,h*64+d]
__global__ __launch_bounds__(256) void k_enc(
    const float* __restrict__ cf, const float* __restrict__ pe_w1, const float* __restrict__ pe_b1,
    const float* __restrict__ pe_w2, const float* __restrict__ pe_b2,
    const float* __restrict__ aiw, const float* __restrict__ aib,
    float* __restrict__ enc_out, float* __restrict__ p_out, int n) {
  __shared__ float cfs[RB][FEAT];
  __shared__ float h1[RB][H];
  __shared__ float encS[RB][H];
  __shared__ float qS[RB][H];
  const int j = threadIdx.x;
  const int n0 = blockIdx.x * RB;
  for (int idx = j; idx < RB * FEAT; idx += 256) cfs[idx / FEAT][idx % FEAT] = cf[(size_t)n0 * FEAT + idx];
  __syncthreads();
#pragma unroll
  for (int r = 0; r < RB; ++r) {
    float s = pe_b1[j];
#pragma unroll
    for (int f = 0; f < FEAT; ++f) s = fmaf(cfs[r][f], pe_w1[f * H + j], s);
    h1[r][j] = fmaxf(s, 0.f);
  }
  __syncthreads();
  float acc[RB];
#pragma unroll
  for (int r = 0; r < RB; ++r) acc[r] = 0.f;
  for (int k = 0; k < H; k += 4) {
    float w0 = pe_w2[(k + 0) * H + j], w1 = pe_w2[(k + 1) * H + j];
    float w2 = pe_w2[(k + 2) * H + j], w3 = pe_w2[(k + 3) * H + j];
#pragma unroll
    for (int r = 0; r < RB; ++r) {
      const float4 hv = *(const float4*)&h1[r][k];
      acc[r] = fmaf(hv.x, w0, fmaf(hv.y, w1, fmaf(hv.z, w2, fmaf(hv.w, w3, acc[r]))));
    }
  }
#pragma unroll
  for (int r = 0; r < RB; ++r) {
    float e = acc[r] + pe_b2[j];
    encS[r][j] = e;
    enc_out[(size_t)(n0 + r) * H + j] = e;
  }
  __syncthreads();
#pragma unroll
  for (int r = 0; r < RB; ++r) acc[r] = 0.f;
  for (int k = 0; k < H; k += 4) {
    float w0 = aiw[(size_t)(k + 0) * 768 + j], w1 = aiw[(size_t)(k + 1) * 768 + j];
    float w2 = aiw[(size_t)(k + 2) * 768 + j], w3 = aiw[(size_t)(k + 3) * 768 + j];
#pragma unroll
    for (int r = 0; r < RB; ++r) {
      const float4 hv = *(const float4*)&encS[r][k];
      acc[r] = fmaf(hv.x, w0, fmaf(hv.y, w1, fmaf(hv.z, w2, fmaf(hv.w, w3, acc[r]))));
    }
  }
#pragma unroll
  for (int r = 0; r < RB; ++r) qS[r][j] = (acc[r] + aib[j]) * 0.125f;
  __syncthreads();
  for (int h = 0; h < HEADS; ++h) {
    float pp[RB];
#pragma unroll
    for (int r = 0; r < RB; ++r) pp[r] = 0.f;
    for (int d = 0; d < DH; d += 4) {
      const float4 wv = *(const float4*)&aiw[(size_t)j * 768 + H + h * DH + d];
#pragma unroll
      for (int r = 0; r < RB; ++r) {
        const float4 qv = *(const float4*)&qS[r][h * DH + d];
        pp[r] = fmaf(qv.x, wv.x, fmaf(qv.y, wv.y, fmaf(qv.z, wv.z, fmaf(qv.w, wv.w, pp[r]))));
      }
    }
#pragma unroll
    for (int r = 0; r < RB; ++r) p_out[(size_t)(n0 + r) * 1024 + h * H + j] = pp[r];
  }
}

// ---------------- per-clause attention: scores, softmax (mask + all_masked), m, lit_mean
__global__ __launch_bounds__(256) void k_attn(
    const float* __restrict__ lit, const int* __restrict__ mask,
    float* __restrict__ pm, float* __restrict__ lit_mean, int* __restrict__ flags, int n) {
  __shared__ float lit_s[L][H + 1];
  __shared__ float p_s[HEADS][H];
  __shared__ float attn_s[HEADS][L];
  __shared__ int validS[L];
  __shared__ int nvalidS;
  const int j = threadIdx.x;
  const int nn = blockIdx.x;
  const float* litrow = lit + (size_t)nn * (L * H);
#pragma unroll
  for (int t = 0; t < (L * H) / 256; ++t) {
    int idx = t * 256 + j;
    lit_s[idx >> 8][idx & 255] = litrow[idx];
  }
  for (int idx = j; idx < HEADS * H; idx += 256) p_s[idx >> 8][idx & 255] = pm[(size_t)nn * 1024 + idx];
  if (j < L) validS[j] = mask[(size_t)nn * L + j] != 0 ? 1 : 0;
  __syncthreads();
  if (j == 0) {
    int c = 0;
#pragma unroll
    for (int l = 0; l < L; ++l) c += validS[l];
    nvalidS = c;
  }
  __syncthreads();
  const int nvalid = nvalidS;
  const bool allm = (nvalid == 0);
  if (j < HEADS * L) {
    const int h = j >> 5, l = j & 31;
    float s = 0.f;
    for (int c = 0; c < H; ++c) s = fmaf(lit_s[l][c], p_s[h][c], s);
    const bool ok = validS[l] || (allm && l == 0);
    float sv = ok ? s : -INFINITY;
    float mx = sv;
#pragma unroll
    for (int m = 16; m >= 1; m >>= 1) mx = fmaxf(mx, __shfl_xor(mx, m, 64));
    float ex = ok ? __expf(sv - mx) : 0.f;
    float sm = ex;
#pragma unroll
    for (int m = 16; m >= 1; m >>= 1) sm += __shfl_xor(sm, m, 64);
    attn_s[h][l] = ex / sm;
  }
  __syncthreads();
  {
    const float inv = 1.f / fmaxf((float)nvalid, 1.f);
    float lmsum = 0.f;
#pragma unroll
    for (int l = 0; l < L; ++l)
      if (validS[l]) lmsum += lit_s[l][j];
    lit_mean[(size_t)nn * H + j] = lmsum * inv;
#pragma unroll
    for (int h = 0; h < HEADS; ++h) {
      float mm = 0.f;
#pragma unroll
      for (int l = 0; l < L; ++l) mm = fmaf(attn_s[h][l], lit_s[l][j], mm);
      pm[(size_t)nn * 1024 + h * H + j] = mm;
    }
  }
  if (j == 0) flags[nn] = allm ? 1 : 0;
}

// ---------------- ctx[n, h*64+d] = sum_c m[n,h,c]*wv[c, h*64+d] + bv
__global__ __launch_bounds__(256) void k_ctx(
    const float* __restrict__ pm, const float* __restrict__ aiw, const float* __restrict__ aib,
    float* __restrict__ ctx, int n) {
  __shared__ float m_s[RBC][4 * H];
  const int j = threadIdx.x;
  const int n0 = blockIdx.x * RBC;
  for (int idx = j; idx < RBC * 4 * H; idx += 256) m_s[idx >> 10][idx & 1023] = pm[(size_t)n0 * 1024 + idx];
  __syncthreads();
  const int h = j >> 6;
  float acc[RBC];
#pragma unroll
  for (int r = 0; r < RBC; ++r) acc[r] = 0.f;
  for (int c = 0; c < H; c += 2) {
    float w0 = aiw[(size_t)(c + 0) * 768 + 512 + j];
    float w1 = aiw[(size_t)(c + 1) * 768 + 512 + j];
#pragma unroll
    for (int r = 0; r < RBC; ++r) {
      const float2 mv = *(const float2*)&m_s[r][h * H + c];
      acc[r] = fmaf(mv.x, w0, fmaf(mv.y, w1, acc[r]));
    }
  }
  const float bv = aib[512 + j];
#pragma unroll
  for (int r = 0; r < RBC; ++r) ctx[(size_t)(n0 + r) * H + j] = acc[r] + bv;
}

// ---------------- out proj + all_masked zero + LN(out+enc) + lit_mean
__global__ __launch_bounds__(256) void k_out_ln(
    const float* __restrict__ ctx, const float* __restrict__ aow, const float* __restrict__ aob,
    const float* __restrict__ enc, const float* __restrict__ lit_mean, const int* __restrict__ flags,
    const float* __restrict__ g, const float* __restrict__ b,
    float* __restrict__ attn_repr, int n) {
  __shared__ float ctx_s[RB][H];
  __shared__ float v_s[RB][H];
  __shared__ float mu_s[RB], sg_s[RB];
  const int j = threadIdx.x;
  const int n0 = blockIdx.x * RB;
  for (int idx = j; idx < RB * H; idx += 256) ctx_s[idx >> 8][idx & 255] = ctx[(size_t)n0 * H + idx];
  __syncthreads();
  float acc[RB];
#pragma unroll
  for (int r = 0; r < RB; ++r) acc[r] = 0.f;
  for (int k = 0; k < H; k += 4) {
    float w0 = aow[(k + 0) * H + j], w1 = aow[(k + 1) * H + j];
    float w2 = aow[(k + 2) * H + j], w3 = aow[(k + 3) * H + j];
#pragma unroll
    for (int r = 0; r < RB; ++r) {
      const float4 cv = *(const float4*)&ctx_s[r][k];
      acc[r] = fmaf(cv.x, w0, fmaf(cv.y, w1, fmaf(cv.z, w2, fmaf(cv.w, w3, acc[r]))));
    }
  }
#pragma unroll
  for (int r = 0; r < RB; ++r) {
    float o = flags[n0 + r] ? 0.f : (acc[r] + aob[j]);
    v_s[r][j] = o + enc[(size_t)(n0 + r) * H + j];
  }
  __syncthreads();
  const int wid = j >> 6, lane = j & 63;
  for (int r = wid; r < RB; r += 4) {
    float ps = 0.f, pq = 0.f;
#pragma unroll
    for (int t = 0; t < 4; ++t) {
      float v = v_s[r][lane + 64 * t];
      ps += v;
      pq = fmaf(v, v, pq);
    }
    ps = wave_reduce_sum64(ps);
    pq = wave_reduce_sum64(pq);
    if (lane == 0) {
      float mu = ps * (1.f / H);
      mu_s[r] = mu;
      sg_s[r] = rsqrtf(pq * (1.f / H) - mu * mu + LN_EPS);
    }
  }
  __syncthreads();
#pragma unroll
  for (int r = 0; r < RB; ++r) {
    float nv = (v_s[r][j] - mu_s[r]) * sg_s[r] * g[j] + b[j] + lit_mean[(size_t)(n0 + r) * H + j];
    attn_repr[(size_t)(n0 + r) * H + j] = nv;
  }
}

// ---------------- gate/transform + fusion LN
__global__ __launch_bounds__(256) void k_gatetrans(
    const float* __restrict__ attn_repr, const float* __restrict__ enc,
    const float* __restrict__ gw, const float* __restrict__ gb,
    const float* __restrict__ tw, const float* __restrict__ tb,
    const float* __restrict__ g, const float* __restrict__ b,
    float* __restrict__ xout, int n) {
  __shared__ float comb[RB][2 * H];
  __shared__ float v_s[RB][H];
  __shared__ float mu_s[RB], sg_s[RB];
  const int j = threadIdx.x;
  const int n0 = blockIdx.x * RB;
  for (int idx = j; idx < RB * 2 * H; idx += 256) {
    int r = idx >> 9, c = idx & 511;
    comb[r][c] = (c < H) ? attn_repr[(size_t)(n0 + r) * H + c] : enc[(size_t)(n0 + r) * H + (c - H)];
  }
  __syncthreads();
  float ag[RB], at[RB];
#pragma unroll
  for (int r = 0; r < RB; ++r) { ag[r] = 0.f; at[r] = 0.f; }
  for (int k = 0; k < 2 * H; k += 2) {
    float g0 = gw[(k + 0) * H + j], g1 = gw[(k + 1) * H + j];
    float t0 = tw[(k + 0) * H + j], t1 = tw[(k + 1) * H + j];
#pragma unroll
    for (int r = 0; r < RB; ++r) {
      const float2 cv = *(const float2*)&comb[r][k];
      ag[r] = fmaf(cv.x, g0, fmaf(cv.y, g1, ag[r]));
      at[r] = fmaf(cv.x, t0, fmaf(cv.y, t1, at[r]));
    }
  }
#pragma unroll
  for (int r = 0; r < RB; ++r) {
    float gate = 1.f / (1.f + __expf(-(ag[r] + gb[j])));
    float tr = at[r] + tb[j];
    float a = comb[r][j];
    v_s[r][j] = fmaf(gate, a - tr, tr);
  }
  __syncthreads();
  const int wid = j >> 6, lane = j & 63;
  for (int r = wid; r < RB; r += 4) {
    float ps = 0.f, pq = 0.f;
#pragma unroll
    for (int t = 0; t < 4; ++t) {
      float v = v_s[r][lane + 64 * t];
      ps += v;
      pq = fmaf(v, v, pq);
    }
    ps = wave_reduce_sum64(ps);
    pq = wave_reduce_sum64(pq);
    if (lane == 0) {
      float mu = ps * (1.f / H);
      mu_s[r] = mu;
      sg_s[r] = rsqrtf(pq * (1.f / H) - mu * mu + LN_EPS);
    }
  }
  __syncthreads();
#pragma unroll
  for (int r = 0; r < RB; ++r)
    xout[(size_t)(n0 + r) * H + j] = (v_s[r][j] - mu_s[r]) * sg_s[r] * g[j] + b[j];
}

// ---------------- message passing helpers
__global__ void k_zerof(float* __restrict__ p, int count) {
  int i = blockIdx.x * blockDim.x + threadIdx.x;
  if (i < count) p[i] = 0.f;
}

__global__ void k_count(const int* __restrict__ dst, float* __restrict__ cnt, int e) {
  int i = blockIdx.x * blockDim.x + threadIdx.x;
  if (i < e) atomicAdd(&cnt[dst[i]], 1.f);
}

__global__ __launch_bounds__(256) void k_scatter(
    const float* __restrict__ x, const int* __restrict__ adj, float* __restrict__ agg, int e) {
  const int wid = (int)((blockIdx.x * 256 + threadIdx.x) >> 6);
  const int lane = threadIdx.x & 63;
  if (wid >= e) return;
  const int s = adj[wid], d = adj[e + wid];
  const float4 v = *(const float4*)(x + (size_t)s * H + lane * 4);
  float* ap = agg + (size_t)d * H + lane * 4;
  atomicAdd(ap + 0, v.x);
  atomicAdd(ap + 1, v.y);
  atomicAdd(ap + 2, v.z);
  atomicAdd(ap + 3, v.w);
}

// ---------------- mp layer: upd = relu([x, agg/cnt]@w + b); x = LN(x+upd)
__global__ __launch_bounds__(256) void k_mp(
    const float* __restrict__ xin, const float* __restrict__ agg, const float* __restrict__ cnt,
    const float* __restrict__ w, const float* __restrict__ bias,
    const float* __restrict__ g, const float* __restrict__ b,
    float* __restrict__ xout, int n) {
  __shared__ float cat[RB][2 * H];
  __shared__ float v_s[RB][H];
  __shared__ float mu_s[RB], sg_s[RB];
  const int j = threadIdx.x;
  const int n0 = blockIdx.x * RB;
  for (int idx = j; idx < RB * 2 * H; idx += 256) {
    int r = idx >> 9, c = idx & 511;
    if (c < H) {
      cat[r][c] = xin[(size_t)(n0 + r) * H + c];
    } else {
      float inv = 1.f / fmaxf(cnt[n0 + r], 1.f);
      cat[r][c] = agg[(size_t)(n0 + r) * H + (c - H)] * inv;
    }
  }
  __syncthreads();
  float acc[RB];
#pragma unroll
  for (int r = 0; r < RB; ++r) acc[r] = 0.f;
  for (int k = 0; k < 2 * H; k += 4) {
    float w0 = w[(k + 0) * H + j], w1 = w[(k + 1) * H + j];
    float w2 = w[(k + 2) * H + j], w3 = w[(k + 3) * H + j];
#pragma unroll
    for (int r = 0; r < RB; ++r) {
      const float4 cv = *(const float4*)&cat[r][k];
      acc[r] = fmaf(cv.x, w0, fmaf(cv.y, w1, fmaf(cv.z, w2, fmaf(cv.w, w3, acc[r]))));
    }
  }
#pragma unroll
  for (int r = 0; r < RB; ++r) {
    float u = fmaxf(acc[r] + bias[j], 0.f);
    v_s[r][j] = cat[r][j] + u;
  }
  __syncthreads();
  const int wid = j >> 6, lane = j & 63;
  for (int r = wid; r < RB; r += 4) {
    float ps = 0.f, pq = 0.f;
#pragma unroll
    for (int t = 0; t < 4; ++t) {
      float v = v_s[r][lane + 64 * t];
      ps += v;
      pq = fmaf(v, v, pq);
    }
    ps = wave_reduce_sum64(ps);
    pq = wave_reduce_sum64(pq);
    if (lane == 0) {
      float mu = ps * (1.f / H);
      mu_s[r] = mu;
      sg_s[r] = rsqrtf(pq * (1.f / H) - mu * mu + LN_EPS);
    }
  }
  __syncthreads();
#pragma unroll
  for (int r = 0; r < RB; ++r)
    xout[(size_t)(n0 + r) * H + j] = (v_s[r][j] - mu_s[r]) * sg_s[r] * g[j] + b[j];
}

extern "C" void kernel_launch(void* const* d_in, const int* in_sizes, int n_in,
                              void* d_out, int out_size, void* d_ws, size_t ws_size,
                              hipStream_t stream) {
  const float* lit = (const float*)d_in[0];
  const float* cf = (const float*)d_in[1];
  const int* mask = (const int*)d_in[2];
  const int* adj = (const int*)d_in[3];
  const float* pe_w1 = (const float*)d_in[4];
  const float* pe_b1 = (const float*)d_in[5];
  const float* pe_w2 = (const float*)d_in[6];
  const float* pe_b2 = (const float*)d_in[7];
  const float* aiw = (const float*)d_in[8];
  const float* aib = (const float*)d_in[9];
  const float* aow = (const float*)d_in[10];
  const float* aob = (const float*)d_in[11];
  const float* attn_ln_g = (const float*)d_in[12];
  const float* attn_ln_b = (const float*)d_in[13];
  const float* gate_w = (const float*)d_in[14];
  const float* gate_b = (const float*)d_in[15];
  const float* trans_w = (const float*)d_in[16];
  const float* trans_b = (const float*)d_in[17];
  const float* fus_ln_g = (const float*)d_in[18];
  const float* fus_ln_b = (const float*)d_in[19];
  const float* mp_w = (const float*)d_in[20];
  const float* mp_b = (const float*)d_in[21];
  const float* mp_ln_g = (const float*)d_in[22];
  const float* mp_ln_b = (const float*)d_in[23];

  const int n = in_sizes[1] / FEAT;   // 20000
  const int e = in_sizes[3] / 2;      // 640000

  float* ws = (float*)d_ws;
  size_t off = 0;
  float* bufA = ws + off; off += (size_t)n * H;     // enc
  float* bufP = ws + off; off += (size_t)n * 1024;  // p -> m -> attn_repr
  float* bufB = ws + off; off += (size_t)n * H;     // lit_mean, later x1
  float* bufC = ws + off; off += (size_t)n * H;     // ctx, later agg
  float* cnt = ws + off; off += n;
  int* flags = (int*)(ws + off); off += n;

  float* enc = bufA;
  float* P = bufP;
  float* lit_mean = bufB;
  float* ctx = bufC;
  float* attn_repr = bufP;
  float* x0 = (float*)d_out;  // gatetrans output lives in d_out, consumed by MP0
  float* x1 = bufB;           // lit_mean is dead after k_out_ln
  float* agg = bufC;
  float* xout = (float*)d_out;

  dim3 blk(256);
  k_enc<<<n / RB, blk, 0, stream>>>(cf, pe_w1, pe_b1, pe_w2, pe_b2, aiw, aib, enc, P, n);
  k_attn<<<n, blk, 0, stream>>>(lit, mask, P, lit_mean, flags, n);
  k_ctx<<<n / RBC, blk, 0, stream>>>(P, aiw, aib, ctx, n);
  k_out_ln<<<n / RB, blk, 0, stream>>>(ctx, aow, aob, enc, lit_mean, flags, attn_ln_g, attn_ln_b, attn_repr, n);
  k_gatetrans<<<n / RB, blk, 0, stream>>>(attn_repr, enc, gate_w, gate_b, trans_w, trans_b, fus_ln_g, fus_ln_b, x0, n);

  // layer 0  (agg and cnt are contiguous: zero both in one launch)
  k_zerof<<<(n * H + n + 255) / 256, blk, 0, stream>>>(agg, n * H + n);
  k_count<<<(e + 255) / 256, blk, 0, stream>>>(adj + e, cnt, e);
  k_scatter<<<(e + 3) / 4, blk, 0, stream>>>(x0, adj, agg, e);
  k_mp<<<n / RB, blk, 0, stream>>>(x0, agg, cnt, mp_w, mp_b, mp_ln_g, mp_ln_b, x1, n);
  // layer 1
  k_zerof<<<(n * H + 255) / 256, blk, 0, stream>>>(agg, n * H);
  k_scatter<<<(e + 3) / 4, blk, 0, stream>>>(x1, adj, agg, e);
  k_mp<<<n / RB, blk, 0, stream>>>(x1, agg, cnt, mp_w + 2 * H * H, mp_b + H, mp_ln_g + H, mp_ln_b + H, xout, n);
}

// Round 3
// 1272.402 us; speedup vs baseline: 4.2480x; 4.2480x over previous
//
#include <hip/hip_runtime.h>
#include <math.h>

#define H 256
#define L 32
#define HEADS 4
#define DH 64
#define FEAT 7
#define RB 16
#define RBC 8
#define LN_EPS 1e-5f

__device__ __forceinline__ float wave_reduce_sum64(float v) {
#pragma unroll
  for (int m = 32; m >= 1; m >>= 1) v += __shfl_xor(v, m, 64);
  return v;
}

// ---------------- encoder: enc = relu(cf@w1+b1)@w2+b2 ; q = (enc@wq+bq)/8 ; p[h,c] = sum_d q[h,d]*wk[c,h*64+d]
__global__ __launch_bounds__(256) void k_enc(
    const float* __restrict__ cf, const float* __restrict__ pe_w1, const float* __restrict__ pe_b1,
    const float* __restrict__ pe_w2, const float* __restrict__ pe_b2,
    const float* __restrict__ aiw, const float* __restrict__ aib,
    float* __restrict__ enc_out, float* __restrict__ p_out, int n) {
  __shared__ float cfs[RB][FEAT];
  __shared__ float h1[RB][H];
  __shared__ float encS[RB][H];
  __shared__ float qS[RB][H];
  const int j = threadIdx.x;
  const int n0 = blockIdx.x * RB;
  for (int idx = j; idx < RB * FEAT; idx += 256) cfs[idx / FEAT][idx % FEAT] = cf[(size_t)n0 * FEAT + idx];
  __syncthreads();
#pragma unroll
  for (int r = 0; r < RB; ++r) {
    float s = pe_b1[j];
#pragma unroll
    for (int f = 0; f < FEAT; ++f) s = fmaf(cfs[r][f], pe_w1[f * H + j], s);
    h1[r][j] = fmaxf(s, 0.f);
  }
  __syncthreads();
  float acc[RB];
#pragma unroll
  for (int r = 0; r < RB; ++r) acc[r] = 0.f;
  for (int k = 0; k < H; k += 4) {
    float w0 = pe_w2[(k + 0) * H + j], w1 = pe_w2[(k + 1) * H + j];
    float w2 = pe_w2[(k + 2) * H + j], w3 = pe_w2[(k + 3) * H + j];
#pragma unroll
    for (int r = 0; r < RB; ++r) {
      const float4 hv = *(const float4*)&h1[r][k];
      acc[r] = fmaf(hv.x, w0, fmaf(hv.y, w1, fmaf(hv.z, w2, fmaf(hv.w, w3, acc[r]))));
    }
  }
#pragma unroll
  for (int r = 0; r < RB; ++r) {
    float e = acc[r] + pe_b2[j];
    encS[r][j] = e;
    enc_out[(size_t)(n0 + r) * H + j] = e;
  }
  __syncthreads();
#pragma unroll
  for (int r = 0; r < RB; ++r) acc[r] = 0.f;
  for (int k = 0; k < H; k += 4) {
    float w0 = aiw[(size_t)(k + 0) * 768 + j], w1 = aiw[(size_t)(k + 1) * 768 + j];
    float w2 = aiw[(size_t)(k + 2) * 768 + j], w3 = aiw[(size_t)(k + 3) * 768 + j];
#pragma unroll
    for (int r = 0; r < RB; ++r) {
      const float4 hv = *(const float4*)&encS[r][k];
      acc[r] = fmaf(hv.x, w0, fmaf(hv.y, w1, fmaf(hv.z, w2, fmaf(hv.w, w3, acc[r]))));
    }
  }
#pragma unroll
  for (int r = 0; r < RB; ++r) qS[r][j] = (acc[r] + aib[j]) * 0.125f;
  __syncthreads();
  for (int h = 0; h < HEADS; ++h) {
    float pp[RB];
#pragma unroll
    for (int r = 0; r < RB; ++r) pp[r] = 0.f;
    for (int d = 0; d < DH; d += 4) {
      const float4 wv = *(const float4*)&aiw[(size_t)j * 768 + H + h * DH + d];
#pragma unroll
      for (int r = 0; r < RB; ++r) {
        const float4 qv = *(const float4*)&qS[r][h * DH + d];
        pp[r] = fmaf(qv.x, wv.x, fmaf(qv.y, wv.y, fmaf(qv.z, wv.z, fmaf(qv.w, wv.w, pp[r]))));
      }
    }
#pragma unroll
    for (int r = 0; r < RB; ++r) p_out[(size_t)(n0 + r) * 1024 + h * H + j] = pp[r];
  }
}

// ---------------- per-clause attention: scores, softmax (mask + all_masked), m, lit_mean
__global__ __launch_bounds__(256) void k_attn(
    const float* __restrict__ lit, const int* __restrict__ mask,
    float* __restrict__ pm, float* __restrict__ lit_mean, int* __restrict__ flags, int n) {
  __shared__ float lit_s[L][H + 1];
  __shared__ float p_s[HEADS][H];
  __shared__ float attn_s[HEADS][L];
  __shared__ int validS[L];
  __shared__ int nvalidS;
  const int j = threadIdx.x;
  const int nn = blockIdx.x;
  const float* litrow = lit + (size_t)nn * (L * H);
#pragma unroll
  for (int t = 0; t < (L * H) / 256; ++t) {
    int idx = t * 256 + j;
    lit_s[idx >> 8][idx & 255] = litrow[idx];
  }
  for (int idx = j; idx < HEADS * H; idx += 256) p_s[idx >> 8][idx & 255] = pm[(size_t)nn * 1024 + idx];
  if (j < L) validS[j] = mask[(size_t)nn * L + j] != 0 ? 1 : 0;
  __syncthreads();
  if (j == 0) {
    int c = 0;
#pragma unroll
    for (int l = 0; l < L; ++l) c += validS[l];
    nvalidS = c;
  }
  __syncthreads();
  const int nvalid = nvalidS;
  const bool allm = (nvalid == 0);
  if (j < HEADS * L) {
    const int h = j >> 5, l = j & 31;
    float s = 0.f;
    for (int c = 0; c < H; ++c) s = fmaf(lit_s[l][c], p_s[h][c], s);
    const bool ok = validS[l] || (allm && l == 0);
    float sv = ok ? s : -INFINITY;
    float mx = sv;
#pragma unroll
    for (int m = 16; m >= 1; m >>= 1) mx = fmaxf(mx, __shfl_xor(mx, m, 64));
    float ex = ok ? __expf(sv - mx) : 0.f;
    float sm = ex;
#pragma unroll
    for (int m = 16; m >= 1; m >>= 1) sm += __shfl_xor(sm, m, 64);
    attn_s[h][l] = ex / sm;
  }
  __syncthreads();
  {
    const float inv = 1.f / fmaxf((float)nvalid, 1.f);
    float lmsum = 0.f;
#pragma unroll
    for (int l = 0; l < L; ++l)
      if (validS[l]) lmsum += lit_s[l][j];
    lit_mean[(size_t)nn * H + j] = lmsum * inv;
#pragma unroll
    for (int h = 0; h < HEADS; ++h) {
      float mm = 0.f;
#pragma unroll
      for (int l = 0; l < L; ++l) mm = fmaf(attn_s[h][l], lit_s[l][j], mm);
      pm[(size_t)nn * 1024 + h * H + j] = mm;
    }
  }
  if (j == 0) flags[nn] = allm ? 1 : 0;
}

// ---------------- ctx[n, h*64+d] = sum_c m[n,h,c]*wv[c, h*64+d] + bv
__global__ __launch_bounds__(256) void k_ctx(
    const float* __restrict__ pm, const float* __restrict__ aiw, const float* __restrict__ aib,
    float* __restrict__ ctx, int n) {
  __shared__ float m_s[RBC][4 * H];
  const int j = threadIdx.x;
  const int n0 = blockIdx.x * RBC;
  for (int idx = j; idx < RBC * 4 * H; idx += 256) m_s[idx >> 10][idx & 1023] = pm[(size_t)n0 * 1024 + idx];
  __syncthreads();
  const int h = j >> 6;
  float acc[RBC];
#pragma unroll
  for (int r = 0; r < RBC; ++r) acc[r] = 0.f;
  for (int c = 0; c < H; c += 2) {
    float w0 = aiw[(size_t)(c + 0) * 768 + 512 + j];
    float w1 = aiw[(size_t)(c + 1) * 768 + 512 + j];
#pragma unroll
    for (int r = 0; r < RBC; ++r) {
      const float2 mv = *(const float2*)&m_s[r][h * H + c];
      acc[r] = fmaf(mv.x, w0, fmaf(mv.y, w1, acc[r]));
    }
  }
  const float bv = aib[512 + j];
#pragma unroll
  for (int r = 0; r < RBC; ++r) ctx[(size_t)(n0 + r) * H + j] = acc[r] + bv;
}

// ---------------- out proj + all_masked zero + LN(out+enc) + lit_mean
__global__ __launch_bounds__(256) void k_out_ln(
    const float* __restrict__ ctx, const float* __restrict__ aow, const float* __restrict__ aob,
    const float* __restrict__ enc, const float* __restrict__ lit_mean, const int* __restrict__ flags,
    const float* __restrict__ g, const float* __restrict__ b,
    float* __restrict__ attn_repr, int n) {
  __shared__ float ctx_s[RB][H];
  __shared__ float v_s[RB][H];
  __shared__ float mu_s[RB], sg_s[RB];
  const int j = threadIdx.x;
  const int n0 = blockIdx.x * RB;
  for (int idx = j; idx < RB * H; idx += 256) ctx_s[idx >> 8][idx & 255] = ctx[(size_t)n0 * H + idx];
  __syncthreads();
  float acc[RB];
#pragma unroll
  for (int r = 0; r < RB; ++r) acc[r] = 0.f;
  for (int k = 0; k < H; k += 4) {
    float w0 = aow[(k + 0) * H + j], w1 = aow[(k + 1) * H + j];
    float w2 = aow[(k + 2) * H + j], w3 = aow[(k + 3) * H + j];
#pragma unroll
    for (int r = 0; r < RB; ++r) {
      const float4 cv = *(const float4*)&ctx_s[r][k];
      acc[r] = fmaf(cv.x, w0, fmaf(cv.y, w1, fmaf(cv.z, w2, fmaf(cv.w, w3, acc[r]))));
    }
  }
#pragma unroll
  for (int r = 0; r < RB; ++r) {
    float o = flags[n0 + r] ? 0.f : (acc[r] + aob[j]);
    v_s[r][j] = o + enc[(size_t)(n0 + r) * H + j];
  }
  __syncthreads();
  const int wid = j >> 6, lane = j & 63;
  for (int r = wid; r < RB; r += 4) {
    float ps = 0.f, pq = 0.f;
#pragma unroll
    for (int t = 0; t < 4; ++t) {
      float v = v_s[r][lane + 64 * t];
      ps += v;
      pq = fmaf(v, v, pq);
    }
    ps = wave_reduce_sum64(ps);
    pq = wave_reduce_sum64(pq);
    if (lane == 0) {
      float mu = ps * (1.f / H);
      mu_s[r] = mu;
      sg_s[r] = rsqrtf(pq * (1.f / H) - mu * mu + LN_EPS);
    }
  }
  __syncthreads();
#pragma unroll
  for (int r = 0; r < RB; ++r) {
    float nv = (v_s[r][j] - mu_s[r]) * sg_s[r] * g[j] + b[j] + lit_mean[(size_t)(n0 + r) * H + j];
    attn_repr[(size_t)(n0 + r) * H + j] = nv;
  }
}

// ---------------- gate/transform + fusion LN
__global__ __launch_bounds__(256) void k_gatetrans(
    const float* __restrict__ attn_repr, const float* __restrict__ enc,
    const float* __restrict__ gw, const float* __restrict__ gb,
    const float* __restrict__ tw, const float* __restrict__ tb,
    const float* __restrict__ g, const float* __restrict__ b,
    float* __restrict__ xout, int n) {
  __shared__ float comb[RB][2 * H];
  __shared__ float v_s[RB][H];
  __shared__ float mu_s[RB], sg_s[RB];
  const int j = threadIdx.x;
  const int n0 = blockIdx.x * RB;
  for (int idx = j; idx < RB * 2 * H; idx += 256) {
    int r = idx >> 9, c = idx & 511;
    comb[r][c] = (c < H) ? attn_repr[(size_t)(n0 + r) * H + c] : enc[(size_t)(n0 + r) * H + (c - H)];
  }
  __syncthreads();
  float ag[RB], at[RB];
#pragma unroll
  for (int r = 0; r < RB; ++r) { ag[r] = 0.f; at[r] = 0.f; }
  for (int k = 0; k < 2 * H; k += 2) {
    float g0 = gw[(k + 0) * H + j], g1 = gw[(k + 1) * H + j];
    float t0 = tw[(k + 0) * H + j], t1 = tw[(k + 1) * H + j];
#pragma unroll
    for (int r = 0; r < RB; ++r) {
      const float2 cv = *(const float2*)&comb[r][k];
      ag[r] = fmaf(cv.x, g0, fmaf(cv.y, g1, ag[r]));
      at[r] = fmaf(cv.x, t0, fmaf(cv.y, t1, at[r]));
    }
  }
#pragma unroll
  for (int r = 0; r < RB; ++r) {
    float gate = 1.f / (1.f + __expf(-(ag[r] + gb[j])));
    float tr = at[r] + tb[j];
    float a = comb[r][j];
    v_s[r][j] = fmaf(gate, a - tr, tr);
  }
  __syncthreads();
  const int wid = j >> 6, lane = j & 63;
  for (int r = wid; r < RB; r += 4) {
    float ps = 0.f, pq = 0.f;
#pragma unroll
    for (int t = 0; t < 4; ++t) {
      float v = v_s[r][lane + 64 * t];
      ps += v;
      pq = fmaf(v, v, pq);
    }
    ps = wave_reduce_sum64(ps);
    pq = wave_reduce_sum64(pq);
    if (lane == 0) {
      float mu = ps * (1.f / H);
      mu_s[r] = mu;
      sg_s[r] = rsqrtf(pq * (1.f / H) - mu * mu + LN_EPS);
    }
  }
  __syncthreads();
#pragma unroll
  for (int r = 0; r < RB; ++r)
    xout[(size_t)(n0 + r) * H + j] = (v_s[r][j] - mu_s[r]) * sg_s[r] * g[j] + b[j];
}

// ---------------- CSR build: histogram -> scan -> fill
__global__ void k_zero_int(int* __restrict__ p, int count) {
  int i = blockIdx.x * blockDim.x + threadIdx.x;
  if (i < count) p[i] = 0;
}

__global__ void k_hist(const int* __restrict__ dst, int* __restrict__ hist, int e) {
  int i = blockIdx.x * blockDim.x + threadIdx.x;
  if (i < e) atomicAdd(&hist[dst[i]], 1);
}

// single block, 1024 threads: exclusive scan of hist[0..n) -> row_ptr[0..n], cursor copy
__global__ __launch_bounds__(1024) void k_scan(
    const int* __restrict__ hist, int* __restrict__ row_ptr, int* __restrict__ cursor, int n, int e) {
  __shared__ int part[1024];
  const int t = threadIdx.x;
  const int chunk = (n + 1023) / 1024;
  const int lo = t * chunk;
  const int hi = min(lo + chunk, n);
  int s = 0;
  for (int i = lo; i < hi; ++i) s += hist[i];
  part[t] = s;
  __syncthreads();
  for (int d = 1; d < 1024; d <<= 1) {
    int v = (t >= d) ? part[t - d] : 0;
    __syncthreads();
    part[t] += v;
    __syncthreads();
  }
  int run = (t > 0) ? part[t - 1] : 0;
  for (int i = lo; i < hi; ++i) {
    row_ptr[i] = run;
    cursor[i] = run;
    run += hist[i];
  }
  if (t == 1023) row_ptr[n] = e;
}

__global__ void k_fill(const int* __restrict__ adj, int* __restrict__ cursor,
                       int* __restrict__ edge_src, int e) {
  int i = blockIdx.x * blockDim.x + threadIdx.x;
  if (i < e) {
    int s = adj[i], d = adj[e + i];
    int pos = atomicAdd(&cursor[d], 1);
    edge_src[pos] = s;
  }
}

// ---------------- gather: agg[d] = mean over in-edges of x[src] (pre-normalized)
__global__ __launch_bounds__(256) void k_gather(
    const float* __restrict__ x, const int* __restrict__ edge_src, const int* __restrict__ row_ptr,
    float* __restrict__ agg, int n) {
  const int wid = threadIdx.x >> 6;
  const int lane = threadIdx.x & 63;
  const int d = blockIdx.x * 4 + wid;
  if (d >= n) return;
  const int beg = row_ptr[d], end = row_ptr[d + 1];
  float4 acc = {0.f, 0.f, 0.f, 0.f};
  for (int i = beg; i < end; ++i) {
    const int s = edge_src[i];
    const float4 v = *(const float4*)(x + (size_t)s * H + lane * 4);
    acc.x += v.x; acc.y += v.y; acc.z += v.z; acc.w += v.w;
  }
  const float inv = 1.f / fmaxf((float)(end - beg), 1.f);
  acc.x *= inv; acc.y *= inv; acc.z *= inv; acc.w *= inv;
  *(float4*)(agg + (size_t)d * H + lane * 4) = acc;
}

// ---------------- mp layer: upd = relu([x, aggN]@w + b); x = LN(x+upd)  (agg pre-normalized)
__global__ __launch_bounds__(256) void k_mp(
    const float* __restrict__ xin, const float* __restrict__ agg,
    const float* __restrict__ w, const float* __restrict__ bias,
    const float* __restrict__ g, const float* __restrict__ b,
    float* __restrict__ xout, int n) {
  __shared__ float cat[RB][2 * H];
  __shared__ float v_s[RB][H];
  __shared__ float mu_s[RB], sg_s[RB];
  const int j = threadIdx.x;
  const int n0 = blockIdx.x * RB;
  for (int idx = j; idx < RB * 2 * H; idx += 256) {
    int r = idx >> 9, c = idx & 511;
    cat[r][c] = (c < H) ? xin[(size_t)(n0 + r) * H + c] : agg[(size_t)(n0 + r) * H + (c - H)];
  }
  __syncthreads();
  float acc[RB];
#pragma unroll
  for (int r = 0; r < RB; ++r) acc[r] = 0.f;
  for (int k = 0; k < 2 * H; k += 4) {
    float w0 = w[(k + 0) * H + j], w1 = w[(k + 1) * H + j];
    float w2 = w[(k + 2) * H + j], w3 = w[(k + 3) * H + j];
#pragma unroll
    for (int r = 0; r < RB; ++r) {
      const float4 cv = *(const float4*)&cat[r][k];
      acc[r] = fmaf(cv.x, w0, fmaf(cv.y, w1, fmaf(cv.z, w2, fmaf(cv.w, w3, acc[r]))));
    }
  }
#pragma unroll
  for (int r = 0; r < RB; ++r) {
    float u = fmaxf(acc[r] + bias[j], 0.f);
    v_s[r][j] = cat[r][j] + u;
  }
  __syncthreads();
  const int wid = j >> 6, lane = j & 63;
  for (int r = wid; r < RB; r += 4) {
    float ps = 0.f, pq = 0.f;
#pragma unroll
    for (int t = 0; t < 4; ++t) {
      float v = v_s[r][lane + 64 * t];
      ps += v;
      pq = fmaf(v, v, pq);
    }
    ps = wave_reduce_sum64(ps);
    pq = wave_reduce_sum64(pq);
    if (lane == 0) {
      float mu = ps * (1.f / H);
      mu_s[r] = mu;
      sg_s[r] = rsqrtf(pq * (1.f / H) - mu * mu + LN_EPS);
    }
  }
  __syncthreads();
#pragma unroll
  for (int r = 0; r < RB; ++r)
    xout[(size_t)(n0 + r) * H + j] = (v_s[r][j] - mu_s[r]) * sg_s[r] * g[j] + b[j];
}

extern "C" void kernel_launch(void* const* d_in, const int* in_sizes, int n_in,
                              void* d_out, int out_size, void* d_ws, size_t ws_size,
                              hipStream_t stream) {
  const float* lit = (const float*)d_in[0];
  const float* cf = (const float*)d_in[1];
  const int* mask = (const int*)d_in[2];
  const int* adj = (const int*)d_in[3];
  const float* pe_w1 = (const float*)d_in[4];
  const float* pe_b1 = (const float*)d_in[5];
  const float* pe_w2 = (const float*)d_in[6];
  const float* pe_b2 = (const float*)d_in[7];
  const float* aiw = (const float*)d_in[8];
  const float* aib = (const float*)d_in[9];
  const float* aow = (const float*)d_in[10];
  const float* aob = (const float*)d_in[11];
  const float* attn_ln_g = (const float*)d_in[12];
  const float* attn_ln_b = (const float*)d_in[13];
  const float* gate_w = (const float*)d_in[14];
  const float* gate_b = (const float*)d_in[15];
  const float* trans_w = (const float*)d_in[16];
  const float* trans_b = (const float*)d_in[17];
  const float* fus_ln_g = (const float*)d_in[18];
  const float* fus_ln_b = (const float*)d_in[19];
  const float* mp_w = (const float*)d_in[20];
  const float* mp_b = (const float*)d_in[21];
  const float* mp_ln_g = (const float*)d_in[22];
  const float* mp_ln_b = (const float*)d_in[23];

  const int n = in_sizes[1] / FEAT;   // 20000
  const int e = in_sizes[3] / 2;      // 640000

  float* ws = (float*)d_ws;
  size_t off = 0;
  float* bufA = ws + off; off += (size_t)n * H;     // enc
  float* bufP = ws + off; off += (size_t)n * 1024;  // p -> m ; [0,n*H) attn_repr ; upper 3/4 CSR
  float* bufB = ws + off; off += (size_t)n * H;     // lit_mean -> x1
  float* bufC = ws + off; off += (size_t)n * H;     // ctx -> agg
  int* flags = (int*)(ws + off); off += n;

  float* enc = bufA;
  float* P = bufP;
  float* lit_mean = bufB;
  float* ctx = bufC;
  float* attn_repr = bufP;      // dense n*H, first quarter of bufP
  float* x0 = (float*)d_out;
  float* x1 = bufB;             // lit_mean dead after k_out_ln
  float* agg = bufC;            // ctx dead after k_out_ln
  float* xout = (float*)d_out;

  // CSR arrays live in the dead upper 3/4 of bufP (free after k_ctx consumes m).
  // Need: hist n + row_ptr (n+1) + cursor n + edge_src e  = 3n+1+e ints ≈ 0.7M << n*768
  int* csr_base = (int*)(bufP + (size_t)n * H);
  int* hist = csr_base;
  int* row_ptr = csr_base + n;
  int* cursor = row_ptr + (n + 1);
  int* edge_src = cursor + n;

  dim3 blk(256);
  k_enc<<<n / RB, blk, 0, stream>>>(cf, pe_w1, pe_b1, pe_w2, pe_b2, aiw, aib, enc, P, n);
  k_attn<<<n, blk, 0, stream>>>(lit, mask, P, lit_mean, flags, n);
  k_ctx<<<n / RBC, blk, 0, stream>>>(P, aiw, aib, ctx, n);

  // CSR build (after k_ctx: bufP upper region now free)
  k_zero_int<<<(n + 255) / 256, blk, 0, stream>>>(hist, n);
  k_hist<<<(e + 255) / 256, blk, 0, stream>>>(adj + e, hist, e);
  k_scan<<<1, 1024, 0, stream>>>(hist, row_ptr, cursor, n, e);
  k_fill<<<(e + 255) / 256, blk, 0, stream>>>(adj, cursor, edge_src, e);

  k_out_ln<<<n / RB, blk, 0, stream>>>(ctx, aow, aob, enc, lit_mean, flags, attn_ln_g, attn_ln_b, attn_repr, n);
  k_gatetrans<<<n / RB, blk, 0, stream>>>(attn_repr, enc, gate_w, gate_b, trans_w, trans_b, fus_ln_g, fus_ln_b, x0, n);

  // layer 0
  k_gather<<<(n + 3) / 4, blk, 0, stream>>>(x0, edge_src, row_ptr, agg, n);
  k_mp<<<n / RB, blk, 0, stream>>>(x0, agg, mp_w, mp_b, mp_ln_g, mp_ln_b, x1, n);
  // layer 1
  k_gather<<<(n + 3) / 4, blk, 0, stream>>>(x1, edge_src, row_ptr, agg, n);
  k_mp<<<n / RB, blk, 0, stream>>>(x1, agg, mp_w + 2 * H * H, mp_b + H, mp_ln_g + H, mp_ln_b + H, xout, n);
}

// Round 5
// 1039.262 us; speedup vs baseline: 5.2010x; 1.2243x over previous
//
#include <hip/hip_runtime.h>
#include <math.h>

#define H 256
#define L 32
#define HEADS 4
#define DH 64
#define FEAT 7
#define RB 16
#define RBC 8
#define LN_EPS 1e-5f

typedef __attribute__((ext_vector_type(8))) short bf16x8;
typedef __attribute__((ext_vector_type(4))) float f32x4;

__device__ __forceinline__ float wave_reduce_sum64(float v) {
#pragma unroll
  for (int m = 32; m >= 1; m >>= 1) v += __shfl_xor(v, m, 64);
  return v;
}

__device__ __forceinline__ short bf16rne(float f) {
  unsigned u = __float_as_uint(f);
  unsigned r = (u + 0x7FFFu + ((u >> 16) & 1u)) >> 16;
  return (short)r;
}

// ---------------- encoder: enc = relu(cf@w1+b1)@w2+b2 ; q = (enc@wq+bq)/8 ; p[h,c] = sum_d q[h,d]*wk[c,h*64+d]
__global__ __launch_bounds__(256) void k_enc(
    const float* __restrict__ cf, const float* __restrict__ pe_w1, const float* __restrict__ pe_b1,
    const float* __restrict__ pe_w2, const float* __restrict__ pe_b2,
    const float* __restrict__ aiw, const float* __restrict__ aib,
    float* __restrict__ enc_out, float* __restrict__ p_out, int n) {
  __shared__ float cfs[RB][FEAT];
  __shared__ float h1[RB][H];
  __shared__ float encS[RB][H];
  __shared__ float qS[RB][H];
  const int j = threadIdx.x;
  const int n0 = blockIdx.x * RB;
  for (int idx = j; idx < RB * FEAT; idx += 256) cfs[idx / FEAT][idx % FEAT] = cf[(size_t)n0 * FEAT + idx];
  __syncthreads();
#pragma unroll
  for (int r = 0; r < RB; ++r) {
    float s = pe_b1[j];
#pragma unroll
    for (int f = 0; f < FEAT; ++f) s = fmaf(cfs[r][f], pe_w1[f * H + j], s);
    h1[r][j] = fmaxf(s, 0.f);
  }
  __syncthreads();
  float acc[RB];
#pragma unroll
  for (int r = 0; r < RB; ++r) acc[r] = 0.f;
  for (int k = 0; k < H; k += 4) {
    float w0 = pe_w2[(k + 0) * H + j], w1 = pe_w2[(k + 1) * H + j];
    float w2 = pe_w2[(k + 2) * H + j], w3 = pe_w2[(k + 3) * H + j];
#pragma unroll
    for (int r = 0; r < RB; ++r) {
      const float4 hv = *(const float4*)&h1[r][k];
      acc[r] = fmaf(hv.x, w0, fmaf(hv.y, w1, fmaf(hv.z, w2, fmaf(hv.w, w3, acc[r]))));
    }
  }
#pragma unroll
  for (int r = 0; r < RB; ++r) {
    float e = acc[r] + pe_b2[j];
    encS[r][j] = e;
    enc_out[(size_t)(n0 + r) * H + j] = e;
  }
  __syncthreads();
#pragma unroll
  for (int r = 0; r < RB; ++r) acc[r] = 0.f;
  for (int k = 0; k < H; k += 4) {
    float w0 = aiw[(size_t)(k + 0) * 768 + j], w1 = aiw[(size_t)(k + 1) * 768 + j];
    float w2 = aiw[(size_t)(k + 2) * 768 + j], w3 = aiw[(size_t)(k + 3) * 768 + j];
#pragma unroll
    for (int r = 0; r < RB; ++r) {
      const float4 hv = *(const float4*)&encS[r][k];
      acc[r] = fmaf(hv.x, w0, fmaf(hv.y, w1, fmaf(hv.z, w2, fmaf(hv.w, w3, acc[r]))));
    }
  }
#pragma unroll
  for (int r = 0; r < RB; ++r) qS[r][j] = (acc[r] + aib[j]) * 0.125f;
  __syncthreads();
  for (int h = 0; h < HEADS; ++h) {
    float pp[RB];
#pragma unroll
    for (int r = 0; r < RB; ++r) pp[r] = 0.f;
    for (int d = 0; d < DH; d += 4) {
      const float4 wv = *(const float4*)&aiw[(size_t)j * 768 + H + h * DH + d];
#pragma unroll
      for (int r = 0; r < RB; ++r) {
        const float4 qv = *(const float4*)&qS[r][h * DH + d];
        pp[r] = fmaf(qv.x, wv.x, fmaf(qv.y, wv.y, fmaf(qv.z, wv.z, fmaf(qv.w, wv.w, pp[r]))));
      }
    }
#pragma unroll
    for (int r = 0; r < RB; ++r) p_out[(size_t)(n0 + r) * 1024 + h * H + j] = pp[r];
  }
}

// ---------------- per-clause attention: scores, softmax (mask + all_masked), m, lit_mean
__global__ __launch_bounds__(256) void k_attn(
    const float* __restrict__ lit, const int* __restrict__ mask,
    float* __restrict__ pm, float* __restrict__ lit_mean, int* __restrict__ flags, int n) {
  __shared__ float lit_s[L][H + 1];
  __shared__ float p_s[HEADS][H];
  __shared__ float attn_s[HEADS][L];
  __shared__ int validS[L];
  __shared__ int nvalidS;
  const int j = threadIdx.x;
  const int nn = blockIdx.x;
  const float* litrow = lit + (size_t)nn * (L * H);
#pragma unroll
  for (int t = 0; t < (L * H) / 256; ++t) {
    int idx = t * 256 + j;
    lit_s[idx >> 8][idx & 255] = litrow[idx];
  }
  for (int idx = j; idx < HEADS * H; idx += 256) p_s[idx >> 8][idx & 255] = pm[(size_t)nn * 1024 + idx];
  if (j < L) validS[j] = mask[(size_t)nn * L + j] != 0 ? 1 : 0;
  __syncthreads();
  if (j == 0) {
    int c = 0;
#pragma unroll
    for (int l = 0; l < L; ++l) c += validS[l];
    nvalidS = c;
  }
  __syncthreads();
  const int nvalid = nvalidS;
  const bool allm = (nvalid == 0);
  if (j < HEADS * L) {
    const int h = j >> 5, l = j & 31;
    float s = 0.f;
    for (int c = 0; c < H; ++c) s = fmaf(lit_s[l][c], p_s[h][c], s);
    const bool ok = validS[l] || (allm && l == 0);
    float sv = ok ? s : -INFINITY;
    float mx = sv;
#pragma unroll
    for (int m = 16; m >= 1; m >>= 1) mx = fmaxf(mx, __shfl_xor(mx, m, 64));
    float ex = ok ? __expf(sv - mx) : 0.f;
    float sm = ex;
#pragma unroll
    for (int m = 16; m >= 1; m >>= 1) sm += __shfl_xor(sm, m, 64);
    attn_s[h][l] = ex / sm;
  }
  __syncthreads();
  {
    const float inv = 1.f / fmaxf((float)nvalid, 1.f);
    float lmsum = 0.f;
#pragma unroll
    for (int l = 0; l < L; ++l)
      if (validS[l]) lmsum += lit_s[l][j];
    lit_mean[(size_t)nn * H + j] = lmsum * inv;
#pragma unroll
    for (int h = 0; h < HEADS; ++h) {
      float mm = 0.f;
#pragma unroll
      for (int l = 0; l < L; ++l) mm = fmaf(attn_s[h][l], lit_s[l][j], mm);
      pm[(size_t)nn * 1024 + h * H + j] = mm;
    }
  }
  if (j == 0) flags[nn] = allm ? 1 : 0;
}

// ---------------- ctx[n, h*64+d] = sum_c m[n,h,c]*wv[c, h*64+d] + bv
__global__ __launch_bounds__(256) void k_ctx(
    const float* __restrict__ pm, const float* __restrict__ aiw, const float* __restrict__ aib,
    float* __restrict__ ctx, int n) {
  __shared__ float m_s[RBC][4 * H];
  const int j = threadIdx.x;
  const int n0 = blockIdx.x * RBC;
  for (int idx = j; idx < RBC * 4 * H; idx += 256) m_s[idx >> 10][idx & 1023] = pm[(size_t)n0 * 1024 + idx];
  __syncthreads();
  const int h = j >> 6;
  float acc[RBC];
#pragma unroll
  for (int r = 0; r < RBC; ++r) acc[r] = 0.f;
  for (int c = 0; c < H; c += 2) {
    float w0 = aiw[(size_t)(c + 0) * 768 + 512 + j];
    float w1 = aiw[(size_t)(c + 1) * 768 + 512 + j];
#pragma unroll
    for (int r = 0; r < RBC; ++r) {
      const float2 mv = *(const float2*)&m_s[r][h * H + c];
      acc[r] = fmaf(mv.x, w0, fmaf(mv.y, w1, acc[r]));
    }
  }
  const float bv = aib[512 + j];
#pragma unroll
  for (int r = 0; r < RBC; ++r) ctx[(size_t)(n0 + r) * H + j] = acc[r] + bv;
}

// ---------------- out proj + all_masked zero + LN(out+enc) + lit_mean
__global__ __launch_bounds__(256) void k_out_ln(
    const float* __restrict__ ctx, const float* __restrict__ aow, const float* __restrict__ aob,
    const float* __restrict__ enc, const float* __restrict__ lit_mean, const int* __restrict__ flags,
    const float* __restrict__ g, const float* __restrict__ b,
    float* __restrict__ attn_repr, int n) {
  __shared__ float ctx_s[RB][H];
  __shared__ float v_s[RB][H];
  __shared__ float mu_s[RB], sg_s[RB];
  const int j = threadIdx.x;
  const int n0 = blockIdx.x * RB;
  for (int idx = j; idx < RB * H; idx += 256) ctx_s[idx >> 8][idx & 255] = ctx[(size_t)n0 * H + idx];
  __syncthreads();
  float acc[RB];
#pragma unroll
  for (int r = 0; r < RB; ++r) acc[r] = 0.f;
  for (int k = 0; k < H; k += 4) {
    float w0 = aow[(k + 0) * H + j], w1 = aow[(k + 1) * H + j];
    float w2 = aow[(k + 2) * H + j], w3 = aow[(k + 3) * H + j];
#pragma unroll
    for (int r = 0; r < RB; ++r) {
      const float4 cv = *(const float4*)&ctx_s[r][k];
      acc[r] = fmaf(cv.x, w0, fmaf(cv.y, w1, fmaf(cv.z, w2, fmaf(cv.w, w3, acc[r]))));
    }
  }
#pragma unroll
  for (int r = 0; r < RB; ++r) {
    float o = flags[n0 + r] ? 0.f : (acc[r] + aob[j]);
    v_s[r][j] = o + enc[(size_t)(n0 + r) * H + j];
  }
  __syncthreads();
  const int wid = j >> 6, lane = j & 63;
  for (int r = wid; r < RB; r += 4) {
    float ps = 0.f, pq = 0.f;
#pragma unroll
    for (int t = 0; t < 4; ++t) {
      float v = v_s[r][lane + 64 * t];
      ps += v;
      pq = fmaf(v, v, pq);
    }
    ps = wave_reduce_sum64(ps);
    pq = wave_reduce_sum64(pq);
    if (lane == 0) {
      float mu = ps * (1.f / H);
      mu_s[r] = mu;
      sg_s[r] = rsqrtf(pq * (1.f / H) - mu * mu + LN_EPS);
    }
  }
  __syncthreads();
#pragma unroll
  for (int r = 0; r < RB; ++r) {
    float nv = (v_s[r][j] - mu_s[r]) * sg_s[r] * g[j] + b[j] + lit_mean[(size_t)(n0 + r) * H + j];
    attn_repr[(size_t)(n0 + r) * H + j] = nv;
  }
}

// ---------------- weight pack: W[K][N] fp32 -> frag-ordered bf16
// P[((tcol*KS + ks)*64 + lane)*8 + i] = bf16(W[ks*32 + (lane>>4)*8 + i][tcol*16 + (lane&15)])
__global__ __launch_bounds__(256) void k_pack_w(
    const float* __restrict__ W, short* __restrict__ P, int K, int N) {
  const int KS = K / 32;
  const int total = (N / 16) * KS * 64;
  int t = blockIdx.x * 256 + threadIdx.x;
  if (t >= total) return;
  const int lane = t & 63;
  const int ks = (t >> 6) % KS;
  const int tcol = (t >> 6) / KS;
  const int j = tcol * 16 + (lane & 15);
  const int k0 = ks * 32 + (lane >> 4) * 8;
  short v[8];
#pragma unroll
  for (int i = 0; i < 8; ++i) v[i] = bf16rne(W[(size_t)(k0 + i) * N + j]);
  *(int4*)&P[(size_t)t * 8] = *(int4*)v;
}

// ---------------- gate/transform + fusion LN via MFMA (BM=32, N=256, K=512)
__global__ __launch_bounds__(256) void k_gatetrans_mfma(
    const float* __restrict__ attn_repr, const float* __restrict__ enc,
    const short* __restrict__ gwP, const short* __restrict__ twP,
    const float* __restrict__ gb, const float* __restrict__ tb,
    const float* __restrict__ g, const float* __restrict__ b,
    float* __restrict__ xout, int n) {
  __shared__ short As[32][520];           // bf16 A-tile; aliased as float[32][260] in epilogue
  __shared__ float mu_s[32], sg_s[32];
  const int tid = threadIdx.x;
  const int lane = tid & 63, w = tid >> 6;
  const int n0 = blockIdx.x * 32;
  // stage A = [attn_repr | enc] as bf16
  for (int q4 = tid; q4 < 32 * 128; q4 += 256) {
    const int idx = q4 << 2;
    const int r = idx >> 9, c = idx & 511;
    const float* s = (c < H) ? (attn_repr + (size_t)(n0 + r) * H + c)
                             : (enc + (size_t)(n0 + r) * H + (c - H));
    const float4 f = *(const float4*)s;
    short4 hv;
    hv.x = bf16rne(f.x); hv.y = bf16rne(f.y); hv.z = bf16rne(f.z); hv.w = bf16rne(f.w);
    *(short4*)&As[r][c] = hv;
  }
  __syncthreads();
  f32x4 accg[2][4], acct[2][4];
#pragma unroll
  for (int rt = 0; rt < 2; ++rt)
#pragma unroll
    for (int ct = 0; ct < 4; ++ct) { accg[rt][ct] = (f32x4)0.f; acct[rt][ct] = (f32x4)0.f; }
  const int arow = lane & 15;
  const int koff = (lane >> 4) * 8;
#pragma unroll 4
  for (int ks = 0; ks < 16; ++ks) {
    const int k0 = ks * 32 + koff;
    const bf16x8 a0 = *(const bf16x8*)&As[arow][k0];
    const bf16x8 a1 = *(const bf16x8*)&As[16 + arow][k0];
#pragma unroll
    for (int ct = 0; ct < 4; ++ct) {
      const size_t fo = (((size_t)(w * 4 + ct) * 16 + ks) * 64 + lane) * 8;
      const bf16x8 bg = *(const bf16x8*)&gwP[fo];
      const bf16x8 bt = *(const bf16x8*)&twP[fo];
      accg[0][ct] = __builtin_amdgcn_mfma_f32_16x16x32_bf16(a0, bg, accg[0][ct], 0, 0, 0);
      accg[1][ct] = __builtin_amdgcn_mfma_f32_16x16x32_bf16(a1, bg, accg[1][ct], 0, 0, 0);
      acct[0][ct] = __builtin_amdgcn_mfma_f32_16x16x32_bf16(a0, bt, acct[0][ct], 0, 0, 0);
      acct[1][ct] = __builtin_amdgcn_mfma_f32_16x16x32_bf16(a1, bt, acct[1][ct], 0, 0, 0);
    }
  }
  __syncthreads();  // done reading As; reuse as fp32 LN buffer
  float* Vs = (float*)&As[0][0];  // [32][260]
#pragma unroll
  for (int rt = 0; rt < 2; ++rt)
#pragma unroll
    for (int ct = 0; ct < 4; ++ct) {
      const int col = w * 64 + ct * 16 + (lane & 15);
      const float gbv = gb[col], tbv = tb[col];
#pragma unroll
      for (int i = 0; i < 4; ++i) {
        const int rl = rt * 16 + (lane >> 4) * 4 + i;
        const float gate = 1.f / (1.f + __expf(-(accg[rt][ct][i] + gbv)));
        const float tr = acct[rt][ct][i] + tbv;
        const float a = attn_repr[(size_t)(n0 + rl) * H + col];
        Vs[rl * 260 + col] = fmaf(gate, a - tr, tr);
      }
    }
  __syncthreads();
  for (int r = w; r < 32; r += 4) {
    float ps = 0.f, pq = 0.f;
#pragma unroll
    for (int t = 0; t < 4; ++t) {
      float v = Vs[r * 260 + lane + 64 * t];
      ps += v;
      pq = fmaf(v, v, pq);
    }
    ps = wave_reduce_sum64(ps);
    pq = wave_reduce_sum64(pq);
    if (lane == 0) {
      float mu = ps * (1.f / H);
      mu_s[r] = mu;
      sg_s[r] = rsqrtf(pq * (1.f / H) - mu * mu + LN_EPS);
    }
  }
  __syncthreads();
  const float gv = g[tid], bv = b[tid];
  for (int r = 0; r < 32; ++r)
    xout[(size_t)(n0 + r) * H + tid] = (Vs[r * 260 + tid] - mu_s[r]) * sg_s[r] * gv + bv;
}

// ---------------- mp layer via MFMA: upd = relu([x, aggN]@w + b); x = LN(x+upd)
__global__ __launch_bounds__(256) void k_mp_mfma(
    const float* __restrict__ xin, const float* __restrict__ agg,
    const short* __restrict__ wP, const float* __restrict__ bias,
    const float* __restrict__ g, const float* __restrict__ b,
    float* __restrict__ xout, int n) {
  __shared__ short As[32][520];
  __shared__ float mu_s[32], sg_s[32];
  const int tid = threadIdx.x;
  const int lane = tid & 63, w = tid >> 6;
  const int n0 = blockIdx.x * 32;
  for (int q4 = tid; q4 < 32 * 128; q4 += 256) {
    const int idx = q4 << 2;
    const int r = idx >> 9, c = idx & 511;
    const float* s = (c < H) ? (xin + (size_t)(n0 + r) * H + c)
                             : (agg + (size_t)(n0 + r) * H + (c - H));
    const float4 f = *(const float4*)s;
    short4 hv;
    hv.x = bf16rne(f.x); hv.y = bf16rne(f.y); hv.z = bf16rne(f.z); hv.w = bf16rne(f.w);
    *(short4*)&As[r][c] = hv;
  }
  __syncthreads();
  f32x4 acc[2][4];
#pragma unroll
  for (int rt = 0; rt < 2; ++rt)
#pragma unroll
    for (int ct = 0; ct < 4; ++ct) acc[rt][ct] = (f32x4)0.f;
  const int arow = lane & 15;
  const int koff = (lane >> 4) * 8;
#pragma unroll 4
  for (int ks = 0; ks < 16; ++ks) {
    const int k0 = ks * 32 + koff;
    const bf16x8 a0 = *(const bf16x8*)&As[arow][k0];
    const bf16x8 a1 = *(const bf16x8*)&As[16 + arow][k0];
#pragma unroll
    for (int ct = 0; ct < 4; ++ct) {
      const size_t fo = (((size_t)(w * 4 + ct) * 16 + ks) * 64 + lane) * 8;
      const bf16x8 bw = *(const bf16x8*)&wP[fo];
      acc[0][ct] = __builtin_amdgcn_mfma_f32_16x16x32_bf16(a0, bw, acc[0][ct], 0, 0, 0);
      acc[1][ct] = __builtin_amdgcn_mfma_f32_16x16x32_bf16(a1, bw, acc[1][ct], 0, 0, 0);
    }
  }
  __syncthreads();
  float* Vs = (float*)&As[0][0];
#pragma unroll
  for (int rt = 0; rt < 2; ++rt)
#pragma unroll
    for (int ct = 0; ct < 4; ++ct) {
      const int col = w * 64 + ct * 16 + (lane & 15);
      const float bsv = bias[col];
#pragma unroll
      for (int i = 0; i < 4; ++i) {
        const int rl = rt * 16 + (lane >> 4) * 4 + i;
        const float u = fmaxf(acc[rt][ct][i] + bsv, 0.f);
        const float xv = xin[(size_t)(n0 + rl) * H + col];
        Vs[rl * 260 + col] = xv + u;
      }
    }
  __syncthreads();
  for (int r = w; r < 32; r += 4) {
    float ps = 0.f, pq = 0.f;
#pragma unroll
    for (int t = 0; t < 4; ++t) {
      float v = Vs[r * 260 + lane + 64 * t];
      ps += v;
      pq = fmaf(v, v, pq);
    }
    ps = wave_reduce_sum64(ps);
    pq = wave_reduce_sum64(pq);
    if (lane == 0) {
      float mu = ps * (1.f / H);
      mu_s[r] = mu;
      sg_s[r] = rsqrtf(pq * (1.f / H) - mu * mu + LN_EPS);
    }
  }
  __syncthreads();
  const float gv = g[tid], bv = b[tid];
  for (int r = 0; r < 32; ++r)
    xout[(size_t)(n0 + r) * H + tid] = (Vs[r * 260 + tid] - mu_s[r]) * sg_s[r] * gv + bv;
}

// ---------------- CSR build: histogram -> scan -> fill
__global__ void k_zero_int(int* __restrict__ p, int count) {
  int i = blockIdx.x * blockDim.x + threadIdx.x;
  if (i < count) p[i] = 0;
}

__global__ void k_hist(const int* __restrict__ dst, int* __restrict__ hist, int e) {
  int i = blockIdx.x * blockDim.x + threadIdx.x;
  if (i < e) atomicAdd(&hist[dst[i]], 1);
}

__global__ __launch_bounds__(1024) void k_scan(
    const int* __restrict__ hist, int* __restrict__ row_ptr, int* __restrict__ cursor, int n, int e) {
  __shared__ int part[1024];
  const int t = threadIdx.x;
  const int chunk = (n + 1023) / 1024;
  const int lo = t * chunk;
  const int hi = min(lo + chunk, n);
  int s = 0;
  for (int i = lo; i < hi; ++i) s += hist[i];
  part[t] = s;
  __syncthreads();
  for (int d = 1; d < 1024; d <<= 1) {
    int v = (t >= d) ? part[t - d] : 0;
    __syncthreads();
    part[t] += v;
    __syncthreads();
  }
  int run = (t > 0) ? part[t - 1] : 0;
  for (int i = lo; i < hi; ++i) {
    row_ptr[i] = run;
    cursor[i] = run;
    run += hist[i];
  }
  if (t == 1023) row_ptr[n] = e;
}

__global__ void k_fill(const int* __restrict__ adj, int* __restrict__ cursor,
                       int* __restrict__ edge_src, int e) {
  int i = blockIdx.x * blockDim.x + threadIdx.x;
  if (i < e) {
    int s = adj[i], d = adj[e + i];
    int pos = atomicAdd(&cursor[d], 1);
    edge_src[pos] = s;
  }
}

// ---------------- gather: agg[d] = mean over in-edges of x[src] (pre-normalized)
__global__ __launch_bounds__(256) void k_gather(
    const float* __restrict__ x, const int* __restrict__ edge_src, const int* __restrict__ row_ptr,
    float* __restrict__ agg, int n) {
  const int wid = threadIdx.x >> 6;
  const int lane = threadIdx.x & 63;
  const int d = blockIdx.x * 4 + wid;
  if (d >= n) return;
  const int beg = row_ptr[d], end = row_ptr[d + 1];
  float4 acc = {0.f, 0.f, 0.f, 0.f};
  for (int i = beg; i < end; ++i) {
    const int s = edge_src[i];
    const float4 v = *(const float4*)(x + (size_t)s * H + lane * 4);
    acc.x += v.x; acc.y += v.y; acc.z += v.z; acc.w += v.w;
  }
  const float inv = 1.f / fmaxf((float)(end - beg), 1.f);
  acc.x *= inv; acc.y *= inv; acc.z *= inv; acc.w *= inv;
  *(float4*)(agg + (size_t)d * H + lane * 4) = acc;
}

extern "C" void kernel_launch(void* const* d_in, const int* in_sizes, int n_in,
                              void* d_out, int out_size, void* d_ws, size_t ws_size,
                              hipStream_t stream) {
  const float* lit = (const float*)d_in[0];
  const float* cf = (const float*)d_in[1];
  const int* mask = (const int*)d_in[2];
  const int* adj = (const int*)d_in[3];
  const float* pe_w1 = (const float*)d_in[4];
  const float* pe_b1 = (const float*)d_in[5];
  const float* pe_w2 = (const float*)d_in[6];
  const float* pe_b2 = (const float*)d_in[7];
  const float* aiw = (const float*)d_in[8];
  const float* aib = (const float*)d_in[9];
  const float* aow = (const float*)d_in[10];
  const float* aob = (const float*)d_in[11];
  const float* attn_ln_g = (const float*)d_in[12];
  const float* attn_ln_b = (const float*)d_in[13];
  const float* gate_w = (const float*)d_in[14];
  const float* gate_b = (const float*)d_in[15];
  const float* trans_w = (const float*)d_in[16];
  const float* trans_b = (const float*)d_in[17];
  const float* fus_ln_g = (const float*)d_in[18];
  const float* fus_ln_b = (const float*)d_in[19];
  const float* mp_w = (const float*)d_in[20];
  const float* mp_b = (const float*)d_in[21];
  const float* mp_ln_g = (const float*)d_in[22];
  const float* mp_ln_b = (const float*)d_in[23];

  const int n = in_sizes[1] / FEAT;   // 20000
  const int e = in_sizes[3] / 2;      // 640000

  float* ws = (float*)d_ws;
  size_t off = 0;
  float* bufA = ws + off; off += (size_t)n * H;     // enc
  float* bufP = ws + off; off += (size_t)n * 1024;  // p -> m ; [0,n*H) attn_repr ; upper 3/4 CSR
  float* bufB = ws + off; off += (size_t)n * H;     // lit_mean -> x1
  float* bufC = ws + off; off += (size_t)n * H;     // ctx -> agg
  int* flags = (int*)(ws + off); off += n;
  short* wpk = (short*)(ws + off); off += 4 * H * 2 * H / 2;  // 4 packed 512x256 bf16 mats

  float* enc = bufA;
  float* P = bufP;
  float* lit_mean = bufB;
  float* ctx = bufC;
  float* attn_repr = bufP;      // dense n*H, first quarter of bufP
  float* x0 = (float*)d_out;
  float* x1 = bufB;             // lit_mean dead after k_out_ln
  float* agg = bufC;            // ctx dead after k_out_ln
  float* xout = (float*)d_out;

  short* gwP = wpk;
  short* twP = wpk + 131072;
  short* mp0P = wpk + 262144;
  short* mp1P = wpk + 393216;

  int* csr_base = (int*)(bufP + (size_t)n * H);
  int* hist = csr_base;
  int* row_ptr = csr_base + n;
  int* cursor = row_ptr + (n + 1);
  int* edge_src = cursor + n;

  dim3 blk(256);
  const int packBlocks = (16 * 16 * 64 + 255) / 256;  // (N/16)*(K/32)*64 threads
  k_pack_w<<<packBlocks, blk, 0, stream>>>(gate_w, gwP, 2 * H, H);
  k_pack_w<<<packBlocks, blk, 0, stream>>>(trans_w, twP, 2 * H, H);
  k_pack_w<<<packBlocks, blk, 0, stream>>>(mp_w, mp0P, 2 * H, H);
  k_pack_w<<<packBlocks, blk, 0, stream>>>(mp_w + 2 * H * H, mp1P, 2 * H, H);

  k_enc<<<n / RB, blk, 0, stream>>>(cf, pe_w1, pe_b1, pe_w2, pe_b2, aiw, aib, enc, P, n);
  k_attn<<<n, blk, 0, stream>>>(lit, mask, P, lit_mean, flags, n);
  k_ctx<<<n / RBC, blk, 0, stream>>>(P, aiw, aib, ctx, n);

  // CSR build (after k_ctx: bufP upper region now free)
  k_zero_int<<<(n + 255) / 256, blk, 0, stream>>>(hist, n);
  k_hist<<<(e + 255) / 256, blk, 0, stream>>>(adj + e, hist, e);
  k_scan<<<1, 1024, 0, stream>>>(hist, row_ptr, cursor, n, e);
  k_fill<<<(e + 255) / 256, blk, 0, stream>>>(adj, cursor, edge_src, e);

  k_out_ln<<<n / RB, blk, 0, stream>>>(ctx, aow, aob, enc, lit_mean, flags, attn_ln_g, attn_ln_b, attn_repr, n);
  k_gatetrans_mfma<<<n / 32, blk, 0, stream>>>(attn_repr, enc, gwP, twP, gate_b, trans_b, fus_ln_g, fus_ln_b, x0, n);

  // layer 0
  k_gather<<<(n + 3) / 4, blk, 0, stream>>>(x0, edge_src, row_ptr, agg, n);
  k_mp_mfma<<<n / 32, blk, 0, stream>>>(x0, agg, mp0P, mp_b, mp_ln_g, mp_ln_b, x1, n);
  // layer 1
  k_gather<<<(n + 3) / 4, blk, 0, stream>>>(x1, edge_src, row_ptr, agg, n);
  k_mp_mfma<<<n / 32, blk, 0, stream>>>(x1, agg, mp1P, mp_b + H, mp_ln_g + H, mp_ln_b + H, xout, n);
}

// Round 6
// 805.336 us; speedup vs baseline: 6.7117x; 1.2905x over previous
//
#include <hip/hip_runtime.h>
#include <math.h>

#define H 256
#define L 32
#define HEADS 4
#define FEAT 7
#define LN_EPS 1e-5f

typedef __attribute__((ext_vector_type(8))) short bf16x8;
typedef __attribute__((ext_vector_type(4))) float f32x4;

__device__ __forceinline__ float wave_reduce_sum64(float v) {
#pragma unroll
  for (int m = 32; m >= 1; m >>= 1) v += __shfl_xor(v, m, 64);
  return v;
}

__device__ __forceinline__ short bf16rne(float f) {
  unsigned u = __float_as_uint(f);
  unsigned r = (u + 0x7FFFu + ((u >> 16) & 1u)) >> 16;
  return (short)r;
}

__device__ __forceinline__ float bf2f(short s) {
  return __uint_as_float(((unsigned)(unsigned short)s) << 16);
}

// ---------------- generic weight pack: W[K][N] fp32 -> frag-ordered bf16
__global__ __launch_bounds__(256) void k_pack_w(
    const float* __restrict__ W, short* __restrict__ P, int K, int N) {
  const int KS = K / 32;
  const int total = (N / 16) * KS * 64;
  int t = blockIdx.x * 256 + threadIdx.x;
  if (t >= total) return;
  const int lane = t & 63;
  const int ks = (t >> 6) % KS;
  const int tcol = (t >> 6) / KS;
  const int j = tcol * 16 + (lane & 15);
  const int k0 = ks * 32 + (lane >> 4) * 8;
  short v[8];
#pragma unroll
  for (int i = 0; i < 8; ++i) v[i] = bf16rne(W[(size_t)(k0 + i) * N + j]);
  *(int4*)&P[(size_t)t * 8] = *(int4*)v;
}

// ---------------- Wqp[k, hc] = 0.125 * sum_d wq[k, h*64+d] * wk[c, h*64+d], packed (N=1024,K=256)
__global__ __launch_bounds__(256) void k_make_wqp(const float* __restrict__ aiw, short* __restrict__ P) {
  int t = blockIdx.x * 256 + threadIdx.x;  // 32768 total
  const int lane = t & 63;
  const int ks = (t >> 6) & 7;
  const int tcol = t >> 9;
  const int col = tcol * 16 + (lane & 15);
  const int h = col >> 8, c = col & 255;
  const int k0 = ks * 32 + (lane >> 4) * 8;
  short v[8];
#pragma unroll
  for (int i = 0; i < 8; ++i) {
    const int k = k0 + i;
    float s = 0.f;
    for (int d = 0; d < 64; ++d)
      s = fmaf(aiw[(size_t)k * 768 + h * 64 + d], aiw[(size_t)c * 768 + 256 + h * 64 + d], s);
    v[i] = bf16rne(0.125f * s);
  }
  *(int4*)&P[(size_t)t * 8] = *(int4*)v;
}

// ---------------- Wbig[hc, j] = sum_d wv[c, h*64+d] * aow[h*64+d, j], packed (N=256,K=1024)
__global__ __launch_bounds__(256) void k_make_wbig(
    const float* __restrict__ aiw, const float* __restrict__ aow, short* __restrict__ P) {
  int t = blockIdx.x * 256 + threadIdx.x;  // 32768 total
  const int lane = t & 63;
  const int ks = (t >> 6) & 31;
  const int tcol = t >> 11;
  const int j = tcol * 16 + (lane & 15);
  const int k0 = ks * 32 + (lane >> 4) * 8;
  short v[8];
#pragma unroll
  for (int i = 0; i < 8; ++i) {
    const int k = k0 + i;
    const int h = k >> 8, c = k & 255;
    float s = 0.f;
    for (int d = 0; d < 64; ++d)
      s = fmaf(aiw[(size_t)c * 768 + 512 + h * 64 + d], aow[(size_t)(h * 64 + d) * 256 + j], s);
    v[i] = bf16rne(s);
  }
  *(int4*)&P[(size_t)t * 8] = *(int4*)v;
}

__global__ void k_bias_p(const float* __restrict__ aiw, const float* __restrict__ aib,
                         float* __restrict__ bias_p) {
  const int col = threadIdx.x + blockIdx.x * 256;  // 1024
  const int h = col >> 8, c = col & 255;
  float s = 0.f;
  for (int d = 0; d < 64; ++d)
    s = fmaf(aib[h * 64 + d], aiw[(size_t)c * 768 + 256 + h * 64 + d], s);
  bias_p[col] = 0.125f * s;
}

__global__ void k_bias_out(const float* __restrict__ aow, const float* __restrict__ aib,
                           const float* __restrict__ aob, float* __restrict__ bias_out) {
  const int j = threadIdx.x;  // 256
  float s = aob[j];
  for (int e = 0; e < 256; ++e) s = fmaf(aib[512 + e], aow[(size_t)e * 256 + j], s);
  bias_out[j] = s;
}

// ---------------- encoder (MFMA): h1 = relu(cf@w1+b1); enc = h1@w2+b2 (bf16 out); p = enc@Wqp + bias_p
__global__ __launch_bounds__(256) void k_enc_mfma(
    const float* __restrict__ cf, const float* __restrict__ pe_w1, const float* __restrict__ pe_b1,
    const short* __restrict__ w2P, const float* __restrict__ pe_b2,
    const short* __restrict__ wqpP, const float* __restrict__ bias_p,
    short* __restrict__ enc_bf16, short* __restrict__ p_bf16, int n) {
  __shared__ float cfs[32][FEAT];
  __shared__ short h1[32][264];
  __shared__ short encS[32][264];
  const int tid = threadIdx.x;
  const int lane = tid & 63, w = tid >> 6;
  const int n0 = blockIdx.x * 32;
  for (int idx = tid; idx < 32 * FEAT; idx += 256) cfs[idx / FEAT][idx % FEAT] = cf[(size_t)n0 * FEAT + idx];
  __syncthreads();
  {
    const int j = tid;
    float wv[FEAT];
#pragma unroll
    for (int f = 0; f < FEAT; ++f) wv[f] = pe_w1[f * H + j];
    const float b1v = pe_b1[j];
    for (int r = 0; r < 32; ++r) {
      float s = b1v;
#pragma unroll
      for (int f = 0; f < FEAT; ++f) s = fmaf(cfs[r][f], wv[f], s);
      h1[r][j] = bf16rne(fmaxf(s, 0.f));
    }
  }
  __syncthreads();
  const int arow = lane & 15;
  const int koff = (lane >> 4) * 8;
  // phase 2: enc = h1 @ w2 (K=256, each wave 64 cols)
  {
    f32x4 acc[2][4];
#pragma unroll
    for (int rt = 0; rt < 2; ++rt)
#pragma unroll
      for (int ct = 0; ct < 4; ++ct) acc[rt][ct] = (f32x4)0.f;
#pragma unroll
    for (int ks = 0; ks < 8; ++ks) {
      const int k0 = ks * 32 + koff;
      const bf16x8 a0 = *(const bf16x8*)&h1[arow][k0];
      const bf16x8 a1 = *(const bf16x8*)&h1[16 + arow][k0];
#pragma unroll
      for (int ct = 0; ct < 4; ++ct) {
        const size_t fo = (((size_t)(w * 4 + ct) * 8 + ks) * 64 + lane) * 8;
        const bf16x8 b = *(const bf16x8*)&w2P[fo];
        acc[0][ct] = __builtin_amdgcn_mfma_f32_16x16x32_bf16(a0, b, acc[0][ct], 0, 0, 0);
        acc[1][ct] = __builtin_amdgcn_mfma_f32_16x16x32_bf16(a1, b, acc[1][ct], 0, 0, 0);
      }
    }
#pragma unroll
    for (int rt = 0; rt < 2; ++rt)
#pragma unroll
      for (int ct = 0; ct < 4; ++ct) {
        const int col = w * 64 + ct * 16 + (lane & 15);
        const float b2v = pe_b2[col];
#pragma unroll
        for (int i = 0; i < 4; ++i) {
          const int row = rt * 16 + (lane >> 4) * 4 + i;
          const short bv = bf16rne(acc[rt][ct][i] + b2v);
          encS[row][col] = bv;
          enc_bf16[(size_t)(n0 + row) * H + col] = bv;
        }
      }
  }
  __syncthreads();
  // phase 3: p = enc @ Wqp + bias_p (N=1024; wave covers 256 cols, 2 chunks of 8 tiles)
#pragma unroll
  for (int chunk = 0; chunk < 2; ++chunk) {
    f32x4 acc[2][8];
#pragma unroll
    for (int rt = 0; rt < 2; ++rt)
#pragma unroll
      for (int c8 = 0; c8 < 8; ++c8) acc[rt][c8] = (f32x4)0.f;
#pragma unroll
    for (int ks = 0; ks < 8; ++ks) {
      const int k0 = ks * 32 + koff;
      const bf16x8 a0 = *(const bf16x8*)&encS[arow][k0];
      const bf16x8 a1 = *(const bf16x8*)&encS[16 + arow][k0];
#pragma unroll
      for (int c8 = 0; c8 < 8; ++c8) {
        const int tcol = w * 16 + chunk * 8 + c8;
        const size_t fo = (((size_t)tcol * 8 + ks) * 64 + lane) * 8;
        const bf16x8 b = *(const bf16x8*)&wqpP[fo];
        acc[0][c8] = __builtin_amdgcn_mfma_f32_16x16x32_bf16(a0, b, acc[0][c8], 0, 0, 0);
        acc[1][c8] = __builtin_amdgcn_mfma_f32_16x16x32_bf16(a1, b, acc[1][c8], 0, 0, 0);
      }
    }
#pragma unroll
    for (int rt = 0; rt < 2; ++rt)
#pragma unroll
      for (int c8 = 0; c8 < 8; ++c8) {
        const int col = w * 256 + (chunk * 8 + c8) * 16 + (lane & 15);
        const float bp = bias_p[col];
#pragma unroll
        for (int i = 0; i < 4; ++i) {
          const int row = rt * 16 + (lane >> 4) * 4 + i;
          p_bf16[(size_t)(n0 + row) * 1024 + col] = bf16rne(acc[rt][c8][i] + bp);
        }
      }
  }
}

// ---------------- per-clause attention: scores (all threads), softmax, m (bf16, in-place), lit_mean
__global__ __launch_bounds__(256) void k_attn(
    const float* __restrict__ lit, const int* __restrict__ mask,
    const short* __restrict__ p_in, short* __restrict__ m_out,
    float* __restrict__ lit_mean, int* __restrict__ flags, int n) {
  __shared__ float lit_s[L][H + 1];
  __shared__ float p_s[HEADS][H];
  __shared__ float scp[2][128];
  __shared__ float attn_s[HEADS][L];
  __shared__ int validS[L];
  __shared__ int nvalidS;
  const int j = threadIdx.x;
  const int nn = blockIdx.x;
  const float* litrow = lit + (size_t)nn * (L * H);
#pragma unroll
  for (int t = 0; t < (L * H) / 256; ++t) {
    int idx = t * 256 + j;
    lit_s[idx >> 8][idx & 255] = litrow[idx];
  }
  for (int idx = j; idx < HEADS * H; idx += 256)
    p_s[idx >> 8][idx & 255] = bf2f(p_in[(size_t)nn * 1024 + idx]);
  if (j < L) validS[j] = mask[(size_t)nn * L + j] != 0 ? 1 : 0;
  __syncthreads();
  if (j == 0) {
    int c = 0;
#pragma unroll
    for (int l = 0; l < L; ++l) c += validS[l];
    nvalidS = c;
  }
  __syncthreads();
  const int nvalid = nvalidS;
  const bool allm = (nvalid == 0);
  // scores: all 256 threads, split-K halves
  {
    const int half = j >> 7, idx = j & 127, h = idx >> 5, l = idx & 31;
    const int c0 = half * 128;
    float s = 0.f;
    for (int c = 0; c < 128; ++c) s = fmaf(lit_s[l][c0 + c], p_s[h][c0 + c], s);
    scp[half][idx] = s;
  }
  __syncthreads();
  if (j < HEADS * L) {
    const int l = j & 31;
    const float sfull = scp[0][j] + scp[1][j];
    const bool ok = validS[l] || (allm && l == 0);
    float sv = ok ? sfull : -INFINITY;
    float mx = sv;
#pragma unroll
    for (int m = 16; m >= 1; m >>= 1) mx = fmaxf(mx, __shfl_xor(mx, m, 64));
    float ex = ok ? __expf(sv - mx) : 0.f;
    float sm = ex;
#pragma unroll
    for (int m = 16; m >= 1; m >>= 1) sm += __shfl_xor(sm, m, 64);
    attn_s[j >> 5][l] = ex / sm;
  }
  __syncthreads();
  {
    const float inv = 1.f / fmaxf((float)nvalid, 1.f);
    float lmsum = 0.f;
#pragma unroll
    for (int l = 0; l < L; ++l)
      if (validS[l]) lmsum += lit_s[l][j];
    lit_mean[(size_t)nn * H + j] = lmsum * inv;
#pragma unroll
    for (int h = 0; h < HEADS; ++h) {
      float mm = 0.f;
#pragma unroll
      for (int l = 0; l < L; ++l) mm = fmaf(attn_s[h][l], lit_s[l][j], mm);
      m_out[(size_t)nn * 1024 + h * H + j] = bf16rne(mm);
    }
  }
  if (j == 0) flags[nn] = allm ? 1 : 0;
}

// ---------------- fused ctx+out-proj (K=1024) + flags + LN(+enc) + lit_mean
__global__ __launch_bounds__(256) void k_ctxout_mfma(
    const short* __restrict__ m_bf16, const short* __restrict__ wbigP, const float* __restrict__ bias_out,
    const short* __restrict__ enc_bf16, const float* __restrict__ lit_mean, const int* __restrict__ flags,
    const float* __restrict__ g, const float* __restrict__ b,
    float* __restrict__ attn_repr, int n) {
  __shared__ float v_s[32][260];
  __shared__ float mu_s[32], sg_s[32];
  __shared__ int flagS[32];
  const int tid = threadIdx.x;
  const int lane = tid & 63, w = tid >> 6;
  const int n0 = blockIdx.x * 32;
  if (tid < 32) flagS[tid] = flags[n0 + tid];
  f32x4 acc[2][4];
#pragma unroll
  for (int rt = 0; rt < 2; ++rt)
#pragma unroll
    for (int ct = 0; ct < 4; ++ct) acc[rt][ct] = (f32x4)0.f;
  const int arow = lane & 15;
  const int koff = (lane >> 4) * 8;
#pragma unroll 8
  for (int ks = 0; ks < 32; ++ks) {
    const size_t abase = (size_t)(n0 + arow) * 1024 + ks * 32 + koff;
    const bf16x8 a0 = *(const bf16x8*)&m_bf16[abase];
    const bf16x8 a1 = *(const bf16x8*)&m_bf16[abase + 16 * 1024];
#pragma unroll
    for (int ct = 0; ct < 4; ++ct) {
      const size_t fo = (((size_t)(w * 4 + ct) * 32 + ks) * 64 + lane) * 8;
      const bf16x8 bw = *(const bf16x8*)&wbigP[fo];
      acc[0][ct] = __builtin_amdgcn_mfma_f32_16x16x32_bf16(a0, bw, acc[0][ct], 0, 0, 0);
      acc[1][ct] = __builtin_amdgcn_mfma_f32_16x16x32_bf16(a1, bw, acc[1][ct], 0, 0, 0);
    }
  }
  __syncthreads();  // flagS visible
#pragma unroll
  for (int rt = 0; rt < 2; ++rt)
#pragma unroll
    for (int ct = 0; ct < 4; ++ct) {
      const int col = w * 64 + ct * 16 + (lane & 15);
      const float bo = bias_out[col];
#pragma unroll
      for (int i = 0; i < 4; ++i) {
        const int row = rt * 16 + (lane >> 4) * 4 + i;
        const float o = flagS[row] ? 0.f : (acc[rt][ct][i] + bo);
        v_s[row][col] = o + bf2f(enc_bf16[(size_t)(n0 + row) * H + col]);
      }
    }
  __syncthreads();
  for (int r = w; r < 32; r += 4) {
    float ps = 0.f, pq = 0.f;
#pragma unroll
    for (int t = 0; t < 4; ++t) {
      float v = v_s[r][lane + 64 * t];
      ps += v;
      pq = fmaf(v, v, pq);
    }
    ps = wave_reduce_sum64(ps);
    pq = wave_reduce_sum64(pq);
    if (lane == 0) {
      float mu = ps * (1.f / H);
      mu_s[r] = mu;
      sg_s[r] = rsqrtf(pq * (1.f / H) - mu * mu + LN_EPS);
    }
  }
  __syncthreads();
  const float gv = g[tid], bv = b[tid];
  for (int r = 0; r < 32; ++r)
    attn_repr[(size_t)(n0 + r) * H + tid] =
        (v_s[r][tid] - mu_s[r]) * sg_s[r] * gv + bv + lit_mean[(size_t)(n0 + r) * H + tid];
}

// ---------------- gate/transform + fusion LN via MFMA; writes x fp32 + bf16
__global__ __launch_bounds__(256) void k_gatetrans_mfma(
    const float* __restrict__ attn_repr, const short* __restrict__ enc_bf16,
    const short* __restrict__ gwP, const short* __restrict__ twP,
    const float* __restrict__ gb, const float* __restrict__ tb,
    const float* __restrict__ g, const float* __restrict__ b,
    float* __restrict__ xout, short* __restrict__ xout_bf, int n) {
  __shared__ short As[32][520];
  __shared__ float mu_s[32], sg_s[32];
  const int tid = threadIdx.x;
  const int lane = tid & 63, w = tid >> 6;
  const int n0 = blockIdx.x * 32;
  for (int q4 = tid; q4 < 32 * 64; q4 += 256) {
    const int idx = q4 << 2;
    const int r = idx >> 8, c = idx & 255;
    const float4 f = *(const float4*)(attn_repr + (size_t)(n0 + r) * H + c);
    short4 hv;
    hv.x = bf16rne(f.x); hv.y = bf16rne(f.y); hv.z = bf16rne(f.z); hv.w = bf16rne(f.w);
    *(short4*)&As[r][c] = hv;
  }
  for (int q8 = tid; q8 < 32 * 32; q8 += 256) {
    const int idx = q8 << 3;
    const int r = idx >> 8, c = idx & 255;
    *(int4*)&As[r][256 + c] = *(const int4*)&enc_bf16[(size_t)(n0 + r) * H + c];
  }
  __syncthreads();
  f32x4 accg[2][4], acct[2][4];
#pragma unroll
  for (int rt = 0; rt < 2; ++rt)
#pragma unroll
    for (int ct = 0; ct < 4; ++ct) { accg[rt][ct] = (f32x4)0.f; acct[rt][ct] = (f32x4)0.f; }
  const int arow = lane & 15;
  const int koff = (lane >> 4) * 8;
#pragma unroll 4
  for (int ks = 0; ks < 16; ++ks) {
    const int k0 = ks * 32 + koff;
    const bf16x8 a0 = *(const bf16x8*)&As[arow][k0];
    const bf16x8 a1 = *(const bf16x8*)&As[16 + arow][k0];
#pragma unroll
    for (int ct = 0; ct < 4; ++ct) {
      const size_t fo = (((size_t)(w * 4 + ct) * 16 + ks) * 64 + lane) * 8;
      const bf16x8 bg = *(const bf16x8*)&gwP[fo];
      const bf16x8 bt = *(const bf16x8*)&twP[fo];
      accg[0][ct] = __builtin_amdgcn_mfma_f32_16x16x32_bf16(a0, bg, accg[0][ct], 0, 0, 0);
      accg[1][ct] = __builtin_amdgcn_mfma_f32_16x16x32_bf16(a1, bg, accg[1][ct], 0, 0, 0);
      acct[0][ct] = __builtin_amdgcn_mfma_f32_16x16x32_bf16(a0, bt, acct[0][ct], 0, 0, 0);
      acct[1][ct] = __builtin_amdgcn_mfma_f32_16x16x32_bf16(a1, bt, acct[1][ct], 0, 0, 0);
    }
  }
  __syncthreads();
  float* Vs = (float*)&As[0][0];  // [32][260]
#pragma unroll
  for (int rt = 0; rt < 2; ++rt)
#pragma unroll
    for (int ct = 0; ct < 4; ++ct) {
      const int col = w * 64 + ct * 16 + (lane & 15);
      const float gbv = gb[col], tbv = tb[col];
#pragma unroll
      for (int i = 0; i < 4; ++i) {
        const int rl = rt * 16 + (lane >> 4) * 4 + i;
        const float gate = 1.f / (1.f + __expf(-(accg[rt][ct][i] + gbv)));
        const float tr = acct[rt][ct][i] + tbv;
        const float a = attn_repr[(size_t)(n0 + rl) * H + col];
        Vs[rl * 260 + col] = fmaf(gate, a - tr, tr);
      }
    }
  __syncthreads();
  for (int r = w; r < 32; r += 4) {
    float ps = 0.f, pq = 0.f;
#pragma unroll
    for (int t = 0; t < 4; ++t) {
      float v = Vs[r * 260 + lane + 64 * t];
      ps += v;
      pq = fmaf(v, v, pq);
    }
    ps = wave_reduce_sum64(ps);
    pq = wave_reduce_sum64(pq);
    if (lane == 0) {
      float mu = ps * (1.f / H);
      mu_s[r] = mu;
      sg_s[r] = rsqrtf(pq * (1.f / H) - mu * mu + LN_EPS);
    }
  }
  __syncthreads();
  const float gv = g[tid], bv = b[tid];
  for (int r = 0; r < 32; ++r) {
    const float val = (Vs[r * 260 + tid] - mu_s[r]) * sg_s[r] * gv + bv;
    xout[(size_t)(n0 + r) * H + tid] = val;
    xout_bf[(size_t)(n0 + r) * H + tid] = bf16rne(val);
  }
}

// ---------------- mp layer via MFMA (bf16 A inputs): upd = relu([x, aggN]@w + b); x = LN(x+upd)
__global__ __launch_bounds__(256) void k_mp_mfma(
    const float* __restrict__ xin, const short* __restrict__ xin_bf, const short* __restrict__ agg_bf,
    const short* __restrict__ wP, const float* __restrict__ bias,
    const float* __restrict__ g, const float* __restrict__ b,
    float* __restrict__ xout, short* __restrict__ xout_bf, int n) {
  __shared__ short As[32][520];
  __shared__ float mu_s[32], sg_s[32];
  const int tid = threadIdx.x;
  const int lane = tid & 63, w = tid >> 6;
  const int n0 = blockIdx.x * 32;
  for (int q8 = tid; q8 < 32 * 64; q8 += 256) {
    const int idx = q8 << 3;
    const int r = idx >> 9, c = idx & 511;
    const short* src = (c < H) ? &xin_bf[(size_t)(n0 + r) * H + c]
                               : &agg_bf[(size_t)(n0 + r) * H + (c - H)];
    *(int4*)&As[r][c] = *(const int4*)src;
  }
  __syncthreads();
  f32x4 acc[2][4];
#pragma unroll
  for (int rt = 0; rt < 2; ++rt)
#pragma unroll
    for (int ct = 0; ct < 4; ++ct) acc[rt][ct] = (f32x4)0.f;
  const int arow = lane & 15;
  const int koff = (lane >> 4) * 8;
#pragma unroll 4
  for (int ks = 0; ks < 16; ++ks) {
    const int k0 = ks * 32 + koff;
    const bf16x8 a0 = *(const bf16x8*)&As[arow][k0];
    const bf16x8 a1 = *(const bf16x8*)&As[16 + arow][k0];
#pragma unroll
    for (int ct = 0; ct < 4; ++ct) {
      const size_t fo = (((size_t)(w * 4 + ct) * 16 + ks) * 64 + lane) * 8;
      const bf16x8 bw = *(const bf16x8*)&wP[fo];
      acc[0][ct] = __builtin_amdgcn_mfma_f32_16x16x32_bf16(a0, bw, acc[0][ct], 0, 0, 0);
      acc[1][ct] = __builtin_amdgcn_mfma_f32_16x16x32_bf16(a1, bw, acc[1][ct], 0, 0, 0);
    }
  }
  __syncthreads();
  float* Vs = (float*)&As[0][0];
#pragma unroll
  for (int rt = 0; rt < 2; ++rt)
#pragma unroll
    for (int ct = 0; ct < 4; ++ct) {
      const int col = w * 64 + ct * 16 + (lane & 15);
      const float bsv = bias[col];
#pragma unroll
      for (int i = 0; i < 4; ++i) {
        const int rl = rt * 16 + (lane >> 4) * 4 + i;
        const float u = fmaxf(acc[rt][ct][i] + bsv, 0.f);
        const float xv = xin[(size_t)(n0 + rl) * H + col];
        Vs[rl * 260 + col] = xv + u;
      }
    }
  __syncthreads();
  for (int r = w; r < 32; r += 4) {
    float ps = 0.f, pq = 0.f;
#pragma unroll
    for (int t = 0; t < 4; ++t) {
      float v = Vs[r * 260 + lane + 64 * t];
      ps += v;
      pq = fmaf(v, v, pq);
    }
    ps = wave_reduce_sum64(ps);
    pq = wave_reduce_sum64(pq);
    if (lane == 0) {
      float mu = ps * (1.f / H);
      mu_s[r] = mu;
      sg_s[r] = rsqrtf(pq * (1.f / H) - mu * mu + LN_EPS);
    }
  }
  __syncthreads();
  const float gv = g[tid], bv = b[tid];
  for (int r = 0; r < 32; ++r) {
    const float val = (Vs[r * 260 + tid] - mu_s[r]) * sg_s[r] * gv + bv;
    xout[(size_t)(n0 + r) * H + tid] = val;
    xout_bf[(size_t)(n0 + r) * H + tid] = bf16rne(val);
  }
}

// ---------------- CSR build
__global__ void k_zero_int(int* __restrict__ p, int count) {
  int i = blockIdx.x * blockDim.x + threadIdx.x;
  if (i < count) p[i] = 0;
}

__global__ void k_hist(const int* __restrict__ dst, int* __restrict__ hist, int e) {
  int i = blockIdx.x * blockDim.x + threadIdx.x;
  if (i < e) atomicAdd(&hist[dst[i]], 1);
}

__global__ __launch_bounds__(1024) void k_scan(
    const int* __restrict__ hist, int* __restrict__ row_ptr, int* __restrict__ cursor, int n, int e) {
  __shared__ int part[1024];
  const int t = threadIdx.x;
  const int chunk = (n + 1023) / 1024;
  const int lo = t * chunk;
  const int hi = min(lo + chunk, n);
  int s = 0;
  for (int i = lo; i < hi; ++i) s += hist[i];
  part[t] = s;
  __syncthreads();
  for (int d = 1; d < 1024; d <<= 1) {
    int v = (t >= d) ? part[t - d] : 0;
    __syncthreads();
    part[t] += v;
    __syncthreads();
  }
  int run = (t > 0) ? part[t - 1] : 0;
  for (int i = lo; i < hi; ++i) {
    row_ptr[i] = run;
    cursor[i] = run;
    run += hist[i];
  }
  if (t == 1023) row_ptr[n] = e;
}

__global__ void k_fill(const int* __restrict__ adj, int* __restrict__ cursor,
                       int* __restrict__ edge_src, int e) {
  int i = blockIdx.x * blockDim.x + threadIdx.x;
  if (i < e) {
    int s = adj[i], d = adj[e + i];
    int pos = atomicAdd(&cursor[d], 1);
    edge_src[pos] = s;
  }
}

// ---------------- gather (bf16 in/out): agg[d] = mean of x[src]
__global__ __launch_bounds__(256) void k_gather(
    const short* __restrict__ x, const int* __restrict__ edge_src, const int* __restrict__ row_ptr,
    short* __restrict__ agg, int n) {
  const int wid = threadIdx.x >> 6;
  const int lane = threadIdx.x & 63;
  const int d = blockIdx.x * 4 + wid;
  if (d >= n) return;
  const int beg = row_ptr[d], end = row_ptr[d + 1];
  float4 acc = {0.f, 0.f, 0.f, 0.f};
  for (int i = beg; i < end; ++i) {
    const int s = edge_src[i];
    const short4 v = *(const short4*)(x + (size_t)s * H + lane * 4);
    acc.x += bf2f(v.x); acc.y += bf2f(v.y); acc.z += bf2f(v.z); acc.w += bf2f(v.w);
  }
  const float inv = 1.f / fmaxf((float)(end - beg), 1.f);
  short4 o;
  o.x = bf16rne(acc.x * inv); o.y = bf16rne(acc.y * inv);
  o.z = bf16rne(acc.z * inv); o.w = bf16rne(acc.w * inv);
  *(short4*)(agg + (size_t)d * H + lane * 4) = o;
}

extern "C" void kernel_launch(void* const* d_in, const int* in_sizes, int n_in,
                              void* d_out, int out_size, void* d_ws, size_t ws_size,
                              hipStream_t stream) {
  const float* lit = (const float*)d_in[0];
  const float* cf = (const float*)d_in[1];
  const int* mask = (const int*)d_in[2];
  const int* adj = (const int*)d_in[3];
  const float* pe_w1 = (const float*)d_in[4];
  const float* pe_b1 = (const float*)d_in[5];
  const float* pe_w2 = (const float*)d_in[6];
  const float* pe_b2 = (const float*)d_in[7];
  const float* aiw = (const float*)d_in[8];
  const float* aib = (const float*)d_in[9];
  const float* aow = (const float*)d_in[10];
  const float* aob = (const float*)d_in[11];
  const float* attn_ln_g = (const float*)d_in[12];
  const float* attn_ln_b = (const float*)d_in[13];
  const float* gate_w = (const float*)d_in[14];
  const float* gate_b = (const float*)d_in[15];
  const float* trans_w = (const float*)d_in[16];
  const float* trans_b = (const float*)d_in[17];
  const float* fus_ln_g = (const float*)d_in[18];
  const float* fus_ln_b = (const float*)d_in[19];
  const float* mp_w = (const float*)d_in[20];
  const float* mp_b = (const float*)d_in[21];
  const float* mp_ln_g = (const float*)d_in[22];
  const float* mp_ln_b = (const float*)d_in[23];

  const int n = in_sizes[1] / FEAT;   // 20000
  const int e = in_sizes[3] / 2;      // 640000

  float* ws = (float*)d_ws;
  size_t off = 0;
  short* enc_bf16 = (short*)(ws + off); off += (size_t)n * 128;
  short* pm_bf16 = (short*)(ws + off); off += (size_t)n * 512;   // p, then m (in-place per clause)
  float* attn_repr = ws + off; off += (size_t)n * 256;
  float* lit_mean = ws + off; off += (size_t)n * 256;
  float* x1 = ws + off; off += (size_t)n * 256;
  short* x0_bf = (short*)(ws + off); off += (size_t)n * 128;
  short* x1_bf = (short*)(ws + off); off += (size_t)n * 128;
  short* agg_bf = (short*)(ws + off); off += (size_t)n * 128;
  int* flags = (int*)(ws + off); off += n;
  int* hist = (int*)(ws + off); off += n;
  int* row_ptr = (int*)(ws + off); off += n + 2;
  int* cursor = (int*)(ws + off); off += n;
  int* edge_src = (int*)(ws + off); off += e;
  short* w2P = (short*)(ws + off); off += 256 * 256 / 2;
  short* wqpP = (short*)(ws + off); off += 256 * 1024 / 2;
  short* wbigP = (short*)(ws + off); off += 1024 * 256 / 2;
  short* gwP = (short*)(ws + off); off += 512 * 256 / 2;
  short* twP = (short*)(ws + off); off += 512 * 256 / 2;
  short* mp0P = (short*)(ws + off); off += 512 * 256 / 2;
  short* mp1P = (short*)(ws + off); off += 512 * 256 / 2;
  float* bias_p = ws + off; off += 1024;
  float* bias_out = ws + off; off += 256;

  float* x0 = (float*)d_out;
  float* xout = (float*)d_out;

  dim3 blk(256);
  // weight prep
  k_pack_w<<<32, blk, 0, stream>>>(pe_w2, w2P, 256, 256);
  k_make_wqp<<<128, blk, 0, stream>>>(aiw, wqpP);
  k_make_wbig<<<128, blk, 0, stream>>>(aiw, aow, wbigP);
  k_bias_p<<<4, blk, 0, stream>>>(aiw, aib, bias_p);
  k_bias_out<<<1, blk, 0, stream>>>(aow, aib, aob, bias_out);
  k_pack_w<<<64, blk, 0, stream>>>(gate_w, gwP, 512, 256);
  k_pack_w<<<64, blk, 0, stream>>>(trans_w, twP, 512, 256);
  k_pack_w<<<64, blk, 0, stream>>>(mp_w, mp0P, 512, 256);
  k_pack_w<<<64, blk, 0, stream>>>(mp_w + 512 * 256, mp1P, 512, 256);

  k_enc_mfma<<<n / 32, blk, 0, stream>>>(cf, pe_w1, pe_b1, w2P, pe_b2, wqpP, bias_p, enc_bf16, pm_bf16, n);
  k_attn<<<n, blk, 0, stream>>>(lit, mask, pm_bf16, pm_bf16, lit_mean, flags, n);

  // CSR build
  k_zero_int<<<(n + 255) / 256, blk, 0, stream>>>(hist, n);
  k_hist<<<(e + 255) / 256, blk, 0, stream>>>(adj + e, hist, e);
  k_scan<<<1, 1024, 0, stream>>>(hist, row_ptr, cursor, n, e);
  k_fill<<<(e + 255) / 256, blk, 0, stream>>>(adj, cursor, edge_src, e);

  k_ctxout_mfma<<<n / 32, blk, 0, stream>>>(pm_bf16, wbigP, bias_out, enc_bf16, lit_mean, flags,
                                            attn_ln_g, attn_ln_b, attn_repr, n);
  k_gatetrans_mfma<<<n / 32, blk, 0, stream>>>(attn_repr, enc_bf16, gwP, twP, gate_b, trans_b,
                                               fus_ln_g, fus_ln_b, x0, x0_bf, n);
  // layer 0
  k_gather<<<(n + 3) / 4, blk, 0, stream>>>(x0_bf, edge_src, row_ptr, agg_bf, n);
  k_mp_mfma<<<n / 32, blk, 0, stream>>>(x0, x0_bf, agg_bf, mp0P, mp_b, mp_ln_g, mp_ln_b, x1, x1_bf, n);
  // layer 1
  k_gather<<<(n + 3) / 4, blk, 0, stream>>>(x1_bf, edge_src, row_ptr, agg_bf, n);
  k_mp_mfma<<<n / 32, blk, 0, stream>>>(x1, x1_bf, agg_bf, mp1P, mp_b + 256, mp_ln_g + 256, mp_ln_b + 256,
                                        xout, x0_bf, n);
}

// Round 7
// 657.535 us; speedup vs baseline: 8.2204x; 1.2248x over previous
//
#include <hip/hip_runtime.h>
#include <math.h>

#define H 256
#define L 32
#define HEADS 4
#define FEAT 7
#define LN_EPS 1e-5f

typedef __attribute__((ext_vector_type(8))) short bf16x8;
typedef __attribute__((ext_vector_type(4))) float f32x4;

__device__ __forceinline__ float wave_reduce_sum64(float v) {
#pragma unroll
  for (int m = 32; m >= 1; m >>= 1) v += __shfl_xor(v, m, 64);
  return v;
}

__device__ __forceinline__ short bf16rne(float f) {
  unsigned u = __float_as_uint(f);
  unsigned r = (u + 0x7FFFu + ((u >> 16) & 1u)) >> 16;
  return (short)r;
}

__device__ __forceinline__ float bf2f(short s) {
  return __uint_as_float(((unsigned)(unsigned short)s) << 16);
}

// ---------------- generic weight pack: W[K][N] fp32 -> frag-ordered bf16
__global__ __launch_bounds__(256) void k_pack_w(
    const float* __restrict__ W, short* __restrict__ P, int K, int N) {
  const int KS = K / 32;
  const int total = (N / 16) * KS * 64;
  int t = blockIdx.x * 256 + threadIdx.x;
  if (t >= total) return;
  const int lane = t & 63;
  const int ks = (t >> 6) % KS;
  const int tcol = (t >> 6) / KS;
  const int j = tcol * 16 + (lane & 15);
  const int k0 = ks * 32 + (lane >> 4) * 8;
  short v[8];
#pragma unroll
  for (int i = 0; i < 8; ++i) v[i] = bf16rne(W[(size_t)(k0 + i) * N + j]);
  *(int4*)&P[(size_t)t * 8] = *(int4*)v;
}

// 4 mats of K=512,N=256 in one launch (blockIdx.y selects)
__global__ __launch_bounds__(256) void k_pack_w4(
    const float* __restrict__ w0, const float* __restrict__ w1,
    const float* __restrict__ w2, const float* __restrict__ w3,
    short* __restrict__ p0, short* __restrict__ p1,
    short* __restrict__ p2, short* __restrict__ p3) {
  const float* W = (blockIdx.y == 0) ? w0 : (blockIdx.y == 1) ? w1 : (blockIdx.y == 2) ? w2 : w3;
  short* P = (blockIdx.y == 0) ? p0 : (blockIdx.y == 1) ? p1 : (blockIdx.y == 2) ? p2 : p3;
  const int KS = 16;
  int t = blockIdx.x * 256 + threadIdx.x;  // total (256/16)*16*64 = 16384
  const int lane = t & 63;
  const int ks = (t >> 6) % KS;
  const int tcol = (t >> 6) / KS;
  const int j = tcol * 16 + (lane & 15);
  const int k0 = ks * 32 + (lane >> 4) * 8;
  short v[8];
#pragma unroll
  for (int i = 0; i < 8; ++i) v[i] = bf16rne(W[(size_t)(k0 + i) * 256 + j]);
  *(int4*)&P[(size_t)t * 8] = *(int4*)v;
}

// ---------------- Wqp[k, hc] = 0.125 * sum_d wq[k, h*64+d] * wk[c, h*64+d], packed (N=1024,K=256)
__global__ __launch_bounds__(256) void k_make_wqp(const float* __restrict__ aiw, short* __restrict__ P) {
  int t = blockIdx.x * 256 + threadIdx.x;  // 32768 total
  const int lane = t & 63;
  const int ks = (t >> 6) & 7;
  const int tcol = t >> 9;
  const int col = tcol * 16 + (lane & 15);
  const int h = col >> 8, c = col & 255;
  const int k0 = ks * 32 + (lane >> 4) * 8;
  short v[8];
#pragma unroll
  for (int i = 0; i < 8; ++i) {
    const int k = k0 + i;
    float s = 0.f;
    for (int d = 0; d < 64; d += 4) {
      const float4 qa = *(const float4*)&aiw[(size_t)k * 768 + h * 64 + d];
      const float4 ka = *(const float4*)&aiw[(size_t)c * 768 + 256 + h * 64 + d];
      s = fmaf(qa.x, ka.x, fmaf(qa.y, ka.y, fmaf(qa.z, ka.z, fmaf(qa.w, ka.w, s))));
    }
    v[i] = bf16rne(0.125f * s);
  }
  *(int4*)&P[(size_t)t * 8] = *(int4*)v;
}

// ---------------- Wbig[hc, j] = sum_d wv[c, h*64+d] * aow[h*64+d, j], packed (N=256,K=1024)
__global__ __launch_bounds__(256) void k_make_wbig(
    const float* __restrict__ aiw, const float* __restrict__ aow, short* __restrict__ P) {
  int t = blockIdx.x * 256 + threadIdx.x;  // 32768 total
  const int lane = t & 63;
  const int ks = (t >> 6) & 31;
  const int tcol = t >> 11;
  const int j = tcol * 16 + (lane & 15);
  const int k0 = ks * 32 + (lane >> 4) * 8;
  short v[8];
#pragma unroll
  for (int i = 0; i < 8; ++i) {
    const int k = k0 + i;
    const int h = k >> 8, c = k & 255;
    float s = 0.f;
    for (int d = 0; d < 64; ++d)
      s = fmaf(aiw[(size_t)c * 768 + 512 + h * 64 + d], aow[(size_t)(h * 64 + d) * 256 + j], s);
    v[i] = bf16rne(s);
  }
  *(int4*)&P[(size_t)t * 8] = *(int4*)v;
}

__global__ void k_bias_p(const float* __restrict__ aiw, const float* __restrict__ aib,
                         float* __restrict__ bias_p) {
  const int col = threadIdx.x + blockIdx.x * 256;  // 1024
  const int h = col >> 8, c = col & 255;
  float s = 0.f;
  for (int d = 0; d < 64; ++d)
    s = fmaf(aib[h * 64 + d], aiw[(size_t)c * 768 + 256 + h * 64 + d], s);
  bias_p[col] = 0.125f * s;
}

__global__ void k_bias_out(const float* __restrict__ aow, const float* __restrict__ aib,
                           const float* __restrict__ aob, float* __restrict__ bias_out) {
  const int j = threadIdx.x;  // 256
  float s = aob[j];
  for (int e = 0; e < 256; ++e) s = fmaf(aib[512 + e], aow[(size_t)e * 256 + j], s);
  bias_out[j] = s;
}

// ---------------- encoder (MFMA): h1 = relu(cf@w1+b1); enc = h1@w2+b2 (bf16); p = enc@Wqp + bias_p
__global__ __launch_bounds__(256) void k_enc_mfma(
    const float* __restrict__ cf, const float* __restrict__ pe_w1, const float* __restrict__ pe_b1,
    const short* __restrict__ w2P, const float* __restrict__ pe_b2,
    const short* __restrict__ wqpP, const float* __restrict__ bias_p,
    short* __restrict__ enc_bf16, short* __restrict__ p_bf16, int n) {
  __shared__ float cfs[32][FEAT];
  __shared__ short h1[32][264];
  __shared__ short encS[32][264];
  const int tid = threadIdx.x;
  const int lane = tid & 63, w = tid >> 6;
  const int n0 = blockIdx.x * 32;
  for (int idx = tid; idx < 32 * FEAT; idx += 256) cfs[idx / FEAT][idx % FEAT] = cf[(size_t)n0 * FEAT + idx];
  __syncthreads();
  {
    const int j = tid;
    float wv[FEAT];
#pragma unroll
    for (int f = 0; f < FEAT; ++f) wv[f] = pe_w1[f * H + j];
    const float b1v = pe_b1[j];
    for (int r = 0; r < 32; ++r) {
      float s = b1v;
#pragma unroll
      for (int f = 0; f < FEAT; ++f) s = fmaf(cfs[r][f], wv[f], s);
      h1[r][j] = bf16rne(fmaxf(s, 0.f));
    }
  }
  __syncthreads();
  const int arow = lane & 15;
  const int koff = (lane >> 4) * 8;
  {
    f32x4 acc[2][4];
#pragma unroll
    for (int rt = 0; rt < 2; ++rt)
#pragma unroll
      for (int ct = 0; ct < 4; ++ct) acc[rt][ct] = (f32x4)0.f;
#pragma unroll
    for (int ks = 0; ks < 8; ++ks) {
      const int k0 = ks * 32 + koff;
      const bf16x8 a0 = *(const bf16x8*)&h1[arow][k0];
      const bf16x8 a1 = *(const bf16x8*)&h1[16 + arow][k0];
#pragma unroll
      for (int ct = 0; ct < 4; ++ct) {
        const size_t fo = (((size_t)(w * 4 + ct) * 8 + ks) * 64 + lane) * 8;
        const bf16x8 b = *(const bf16x8*)&w2P[fo];
        acc[0][ct] = __builtin_amdgcn_mfma_f32_16x16x32_bf16(a0, b, acc[0][ct], 0, 0, 0);
        acc[1][ct] = __builtin_amdgcn_mfma_f32_16x16x32_bf16(a1, b, acc[1][ct], 0, 0, 0);
      }
    }
#pragma unroll
    for (int rt = 0; rt < 2; ++rt)
#pragma unroll
      for (int ct = 0; ct < 4; ++ct) {
        const int col = w * 64 + ct * 16 + (lane & 15);
        const float b2v = pe_b2[col];
#pragma unroll
        for (int i = 0; i < 4; ++i) {
          const int row = rt * 16 + (lane >> 4) * 4 + i;
          const short bv = bf16rne(acc[rt][ct][i] + b2v);
          encS[row][col] = bv;
          enc_bf16[(size_t)(n0 + row) * H + col] = bv;
        }
      }
  }
  __syncthreads();
#pragma unroll
  for (int chunk = 0; chunk < 2; ++chunk) {
    f32x4 acc[2][8];
#pragma unroll
    for (int rt = 0; rt < 2; ++rt)
#pragma unroll
      for (int c8 = 0; c8 < 8; ++c8) acc[rt][c8] = (f32x4)0.f;
#pragma unroll
    for (int ks = 0; ks < 8; ++ks) {
      const int k0 = ks * 32 + koff;
      const bf16x8 a0 = *(const bf16x8*)&encS[arow][k0];
      const bf16x8 a1 = *(const bf16x8*)&encS[16 + arow][k0];
#pragma unroll
      for (int c8 = 0; c8 < 8; ++c8) {
        const int tcol = w * 16 + chunk * 8 + c8;
        const size_t fo = (((size_t)tcol * 8 + ks) * 64 + lane) * 8;
        const bf16x8 b = *(const bf16x8*)&wqpP[fo];
        acc[0][c8] = __builtin_amdgcn_mfma_f32_16x16x32_bf16(a0, b, acc[0][c8], 0, 0, 0);
        acc[1][c8] = __builtin_amdgcn_mfma_f32_16x16x32_bf16(a1, b, acc[1][c8], 0, 0, 0);
      }
    }
#pragma unroll
    for (int rt = 0; rt < 2; ++rt)
#pragma unroll
      for (int c8 = 0; c8 < 8; ++c8) {
        const int col = w * 256 + (chunk * 8 + c8) * 16 + (lane & 15);
        const float bp = bias_p[col];
#pragma unroll
        for (int i = 0; i < 4; ++i) {
          const int row = rt * 16 + (lane >> 4) * 4 + i;
          p_bf16[(size_t)(n0 + row) * 1024 + col] = bf16rne(acc[rt][c8][i] + bp);
        }
      }
  }
}

// ---------------- per-clause attention: MFMA scores (wave 0), softmax, register m-phase
__global__ __launch_bounds__(256) void k_attn(
    const float* __restrict__ lit, const int* __restrict__ mask,
    const short* __restrict__ p_in, short* __restrict__ m_out,
    short* __restrict__ litmean_bf, int* __restrict__ flags, int n) {
  __shared__ short lit_bs[32][264];
  __shared__ float attn_s[32][4];
  __shared__ int validS[32];
  __shared__ int nvalidS;
  const int j = threadIdx.x;
  const int nn = blockIdx.x;
  const float* litrow = lit + (size_t)nn * (L * H);
  float lreg[32];
#pragma unroll
  for (int t = 0; t < 32; ++t) {
    const float v = litrow[t * 256 + j];
    lreg[t] = v;
    lit_bs[t][j] = bf16rne(v);
  }
  if (j < 32) validS[j] = (mask[(size_t)nn * L + j] != 0) ? 1 : 0;
  __syncthreads();
  if (j == 0) {
    int c = 0;
#pragma unroll
    for (int l = 0; l < 32; ++l) c += validS[l];
    nvalidS = c;
  }
  __syncthreads();
  const int nvalid = nvalidS;
  const bool allm = (nvalid == 0);
  if (j < 64) {
    const int lane = j;
    f32x4 sc0 = (f32x4)0.f, sc1 = (f32x4)0.f;
    const int hh = lane & 3;
    const int krow = (lane >> 4) * 8;
    const short* prow = p_in + (size_t)nn * 1024 + hh * 256;
#pragma unroll
    for (int ks = 0; ks < 8; ++ks) {
      const bf16x8 a = *(const bf16x8*)&prow[ks * 32 + krow];
      const bf16x8 b0 = *(const bf16x8*)&lit_bs[lane & 15][ks * 32 + krow];
      const bf16x8 b1 = *(const bf16x8*)&lit_bs[16 + (lane & 15)][ks * 32 + krow];
      sc0 = __builtin_amdgcn_mfma_f32_16x16x32_bf16(a, b0, sc0, 0, 0, 0);
      sc1 = __builtin_amdgcn_mfma_f32_16x16x32_bf16(a, b1, sc1, 0, 0, 0);
    }
    if (lane < 16) {
      const int l0 = lane, l1 = 16 + lane;
      const bool ok0 = validS[l0] || (allm && l0 == 0);
      const bool ok1 = validS[l1] != 0;
#pragma unroll
      for (int i = 0; i < 4; ++i) {  // i = head (D row = i for lanes 0-15)
        float s0 = ok0 ? sc0[i] : -INFINITY;
        float s1 = ok1 ? sc1[i] : -INFINITY;
        float mx = fmaxf(s0, s1);
#pragma unroll
        for (int m = 8; m >= 1; m >>= 1) mx = fmaxf(mx, __shfl_xor(mx, m, 16));
        float e0 = ok0 ? __expf(s0 - mx) : 0.f;
        float e1 = ok1 ? __expf(s1 - mx) : 0.f;
        float sm = e0 + e1;
#pragma unroll
        for (int m = 8; m >= 1; m >>= 1) sm += __shfl_xor(sm, m, 16);
        const float inv = 1.f / sm;
        attn_s[l0][i] = e0 * inv;
        attn_s[l1][i] = e1 * inv;
      }
    }
  }
  __syncthreads();
  {
    const float inv = 1.f / fmaxf((float)nvalid, 1.f);
    float lm = 0.f;
#pragma unroll
    for (int l = 0; l < 32; ++l)
      if (validS[l]) lm += lreg[l];
    litmean_bf[(size_t)nn * H + j] = bf16rne(lm * inv);
    float mm0 = 0.f, mm1 = 0.f, mm2 = 0.f, mm3 = 0.f;
#pragma unroll
    for (int l = 0; l < 32; ++l) {
      const float4 av = *(const float4*)&attn_s[l][0];
      const float lv = lreg[l];
      mm0 = fmaf(av.x, lv, mm0);
      mm1 = fmaf(av.y, lv, mm1);
      mm2 = fmaf(av.z, lv, mm2);
      mm3 = fmaf(av.w, lv, mm3);
    }
    m_out[(size_t)nn * 1024 + 0 * 256 + j] = bf16rne(mm0);
    m_out[(size_t)nn * 1024 + 1 * 256 + j] = bf16rne(mm1);
    m_out[(size_t)nn * 1024 + 2 * 256 + j] = bf16rne(mm2);
    m_out[(size_t)nn * 1024 + 3 * 256 + j] = bf16rne(mm3);
  }
  if (j == 0) flags[nn] = allm ? 1 : 0;
}

// ---------------- fused: ctx/out-proj GEMM + LN1 + gate/trans GEMMs + fusion LN -> x0 bf16
__global__ __launch_bounds__(256) void k_fused(
    const short* __restrict__ m_bf16, const short* __restrict__ wbigP, const float* __restrict__ bias_out,
    const short* __restrict__ enc_bf16, const short* __restrict__ litmean_bf, const int* __restrict__ flags,
    const float* __restrict__ ag, const float* __restrict__ ab,
    const short* __restrict__ gwP, const short* __restrict__ twP,
    const float* __restrict__ gb, const float* __restrict__ tb,
    const float* __restrict__ fg, const float* __restrict__ fb,
    short* __restrict__ xout_bf, int n) {
  __shared__ short As[32][520];   // cols 0-255: attn_repr bf16 (later); 256-511: enc bf16
  __shared__ float v_s[32][260];
  __shared__ float mu_s[32], sg_s[32];
  __shared__ int flagS[32];
  const int tid = threadIdx.x;
  const int lane = tid & 63, w = tid >> 6;
  const int n0 = blockIdx.x * 32;
  // stage enc into As[.][256..512)
  for (int q8 = tid; q8 < 32 * 32; q8 += 256) {
    const int idx = q8 << 3;
    const int r = idx >> 8, c = idx & 255;
    *(int4*)&As[r][256 + c] = *(const int4*)&enc_bf16[(size_t)(n0 + r) * H + c];
  }
  if (tid < 32) flagS[tid] = flags[n0 + tid];
  const int arow = lane & 15;
  const int koff = (lane >> 4) * 8;
  // phase A: ctx+out GEMM (K=1024), A from global m
  f32x4 acc[2][4];
#pragma unroll
  for (int rt = 0; rt < 2; ++rt)
#pragma unroll
    for (int ct = 0; ct < 4; ++ct) acc[rt][ct] = (f32x4)0.f;
#pragma unroll 8
  for (int ks = 0; ks < 32; ++ks) {
    const size_t abase = (size_t)(n0 + arow) * 1024 + ks * 32 + koff;
    const bf16x8 a0 = *(const bf16x8*)&m_bf16[abase];
    const bf16x8 a1 = *(const bf16x8*)&m_bf16[abase + 16 * 1024];
#pragma unroll
    for (int ct = 0; ct < 4; ++ct) {
      const size_t fo = (((size_t)(w * 4 + ct) * 32 + ks) * 64 + lane) * 8;
      const bf16x8 bw = *(const bf16x8*)&wbigP[fo];
      acc[0][ct] = __builtin_amdgcn_mfma_f32_16x16x32_bf16(a0, bw, acc[0][ct], 0, 0, 0);
      acc[1][ct] = __builtin_amdgcn_mfma_f32_16x16x32_bf16(a1, bw, acc[1][ct], 0, 0, 0);
    }
  }
  __syncthreads();  // As-enc + flagS ready
  // epilogue A: v = (flag?0:ctxout) + enc
#pragma unroll
  for (int rt = 0; rt < 2; ++rt)
#pragma unroll
    for (int ct = 0; ct < 4; ++ct) {
      const int col = w * 64 + ct * 16 + (lane & 15);
      const float bo = bias_out[col];
#pragma unroll
      for (int i = 0; i < 4; ++i) {
        const int row = rt * 16 + (lane >> 4) * 4 + i;
        const float o = flagS[row] ? 0.f : (acc[rt][ct][i] + bo);
        v_s[row][col] = o + bf2f(As[row][256 + col]);
      }
    }
  __syncthreads();
  // LN1
  for (int r = w; r < 32; r += 4) {
    float ps = 0.f, pq = 0.f;
#pragma unroll
    for (int t = 0; t < 4; ++t) {
      float v = v_s[r][lane + 64 * t];
      ps += v;
      pq = fmaf(v, v, pq);
    }
    ps = wave_reduce_sum64(ps);
    pq = wave_reduce_sum64(pq);
    if (lane == 0) {
      float mu = ps * (1.f / H);
      mu_s[r] = mu;
      sg_s[r] = rsqrtf(pq * (1.f / H) - mu * mu + LN_EPS);
    }
  }
  __syncthreads();
  // attn_repr -> As bf16 cols 0-255 (includes lit_mean)
  {
    const float agv = ag[tid], abv = ab[tid];
    for (int r = 0; r < 32; ++r) {
      const float val = (v_s[r][tid] - mu_s[r]) * sg_s[r] * agv + abv +
                        bf2f(litmean_bf[(size_t)(n0 + r) * H + tid]);
      As[r][tid] = bf16rne(val);
    }
  }
  __syncthreads();
  // phase B: gate/trans GEMMs (K=512) from As
  f32x4 accg[2][4], acct[2][4];
#pragma unroll
  for (int rt = 0; rt < 2; ++rt)
#pragma unroll
    for (int ct = 0; ct < 4; ++ct) { accg[rt][ct] = (f32x4)0.f; acct[rt][ct] = (f32x4)0.f; }
#pragma unroll 4
  for (int ks = 0; ks < 16; ++ks) {
    const int k0 = ks * 32 + koff;
    const bf16x8 a0 = *(const bf16x8*)&As[arow][k0];
    const bf16x8 a1 = *(const bf16x8*)&As[16 + arow][k0];
#pragma unroll
    for (int ct = 0; ct < 4; ++ct) {
      const size_t fo = (((size_t)(w * 4 + ct) * 16 + ks) * 64 + lane) * 8;
      const bf16x8 bg = *(const bf16x8*)&gwP[fo];
      const bf16x8 bt = *(const bf16x8*)&twP[fo];
      accg[0][ct] = __builtin_amdgcn_mfma_f32_16x16x32_bf16(a0, bg, accg[0][ct], 0, 0, 0);
      accg[1][ct] = __builtin_amdgcn_mfma_f32_16x16x32_bf16(a1, bg, accg[1][ct], 0, 0, 0);
      acct[0][ct] = __builtin_amdgcn_mfma_f32_16x16x32_bf16(a0, bt, acct[0][ct], 0, 0, 0);
      acct[1][ct] = __builtin_amdgcn_mfma_f32_16x16x32_bf16(a1, bt, acct[1][ct], 0, 0, 0);
    }
  }
  // epilogue B: v = gate*(a-tr)+tr  (a = bf16 attn_repr from As)
#pragma unroll
  for (int rt = 0; rt < 2; ++rt)
#pragma unroll
    for (int ct = 0; ct < 4; ++ct) {
      const int col = w * 64 + ct * 16 + (lane & 15);
      const float gbv = gb[col], tbv = tb[col];
#pragma unroll
      for (int i = 0; i < 4; ++i) {
        const int rl = rt * 16 + (lane >> 4) * 4 + i;
        const float gate = 1.f / (1.f + __expf(-(accg[rt][ct][i] + gbv)));
        const float tr = acct[rt][ct][i] + tbv;
        const float a = bf2f(As[rl][col]);
        v_s[rl][col] = fmaf(gate, a - tr, tr);
      }
    }
  __syncthreads();
  // LN2
  for (int r = w; r < 32; r += 4) {
    float ps = 0.f, pq = 0.f;
#pragma unroll
    for (int t = 0; t < 4; ++t) {
      float v = v_s[r][lane + 64 * t];
      ps += v;
      pq = fmaf(v, v, pq);
    }
    ps = wave_reduce_sum64(ps);
    pq = wave_reduce_sum64(pq);
    if (lane == 0) {
      float mu = ps * (1.f / H);
      mu_s[r] = mu;
      sg_s[r] = rsqrtf(pq * (1.f / H) - mu * mu + LN_EPS);
    }
  }
  __syncthreads();
  {
    const float fgv = fg[tid], fbv = fb[tid];
    for (int r = 0; r < 32; ++r)
      xout_bf[(size_t)(n0 + r) * H + tid] = bf16rne((v_s[r][tid] - mu_s[r]) * sg_s[r] * fgv + fbv);
  }
}

// ---------------- mp layer via MFMA (bf16 in, bf16 residual): x' = LN(x + relu([x,agg]@w+b))
__global__ __launch_bounds__(256) void k_mp_mfma(
    const short* __restrict__ xin_bf, const short* __restrict__ agg_bf,
    const short* __restrict__ wP, const float* __restrict__ bias,
    const float* __restrict__ g, const float* __restrict__ b,
    float* __restrict__ xout_f32, short* __restrict__ xout_bf, int n) {
  __shared__ short As[32][520];
  __shared__ float v_s[32][260];
  __shared__ float mu_s[32], sg_s[32];
  const int tid = threadIdx.x;
  const int lane = tid & 63, w = tid >> 6;
  const int n0 = blockIdx.x * 32;
  for (int q8 = tid; q8 < 32 * 64; q8 += 256) {
    const int idx = q8 << 3;
    const int r = idx >> 9, c = idx & 511;
    const short* src = (c < H) ? &xin_bf[(size_t)(n0 + r) * H + c]
                               : &agg_bf[(size_t)(n0 + r) * H + (c - H)];
    *(int4*)&As[r][c] = *(const int4*)src;
  }
  __syncthreads();
  f32x4 acc[2][4];
#pragma unroll
  for (int rt = 0; rt < 2; ++rt)
#pragma unroll
    for (int ct = 0; ct < 4; ++ct) acc[rt][ct] = (f32x4)0.f;
  const int arow = lane & 15;
  const int koff = (lane >> 4) * 8;
#pragma unroll 4
  for (int ks = 0; ks < 16; ++ks) {
    const int k0 = ks * 32 + koff;
    const bf16x8 a0 = *(const bf16x8*)&As[arow][k0];
    const bf16x8 a1 = *(const bf16x8*)&As[16 + arow][k0];
#pragma unroll
    for (int ct = 0; ct < 4; ++ct) {
      const size_t fo = (((size_t)(w * 4 + ct) * 16 + ks) * 64 + lane) * 8;
      const bf16x8 bw = *(const bf16x8*)&wP[fo];
      acc[0][ct] = __builtin_amdgcn_mfma_f32_16x16x32_bf16(a0, bw, acc[0][ct], 0, 0, 0);
      acc[1][ct] = __builtin_amdgcn_mfma_f32_16x16x32_bf16(a1, bw, acc[1][ct], 0, 0, 0);
    }
  }
#pragma unroll
  for (int rt = 0; rt < 2; ++rt)
#pragma unroll
    for (int ct = 0; ct < 4; ++ct) {
      const int col = w * 64 + ct * 16 + (lane & 15);
      const float bsv = bias[col];
#pragma unroll
      for (int i = 0; i < 4; ++i) {
        const int rl = rt * 16 + (lane >> 4) * 4 + i;
        const float u = fmaxf(acc[rt][ct][i] + bsv, 0.f);
        v_s[rl][col] = bf2f(As[rl][col]) + u;
      }
    }
  __syncthreads();
  for (int r = w; r < 32; r += 4) {
    float ps = 0.f, pq = 0.f;
#pragma unroll
    for (int t = 0; t < 4; ++t) {
      float v = v_s[r][lane + 64 * t];
      ps += v;
      pq = fmaf(v, v, pq);
    }
    ps = wave_reduce_sum64(ps);
    pq = wave_reduce_sum64(pq);
    if (lane == 0) {
      float mu = ps * (1.f / H);
      mu_s[r] = mu;
      sg_s[r] = rsqrtf(pq * (1.f / H) - mu * mu + LN_EPS);
    }
  }
  __syncthreads();
  const float gv = g[tid], bv = b[tid];
  for (int r = 0; r < 32; ++r) {
    const float val = (v_s[r][tid] - mu_s[r]) * sg_s[r] * gv + bv;
    if (xout_f32) xout_f32[(size_t)(n0 + r) * H + tid] = val;
    if (xout_bf) xout_bf[(size_t)(n0 + r) * H + tid] = bf16rne(val);
  }
}

// ---------------- CSR build
__global__ void k_zero_int(int* __restrict__ p, int count) {
  int i = blockIdx.x * blockDim.x + threadIdx.x;
  if (i < count) p[i] = 0;
}

__global__ void k_hist(const int* __restrict__ dst, int* __restrict__ hist, int e) {
  int i = blockIdx.x * blockDim.x + threadIdx.x;
  if (i < e) atomicAdd(&hist[dst[i]], 1);
}

__global__ __launch_bounds__(1024) void k_scan(
    const int* __restrict__ hist, int* __restrict__ row_ptr, int* __restrict__ cursor, int n, int e) {
  __shared__ int part[1024];
  const int t = threadIdx.x;
  const int chunk = (n + 1023) / 1024;
  const int lo = t * chunk;
  const int hi = min(lo + chunk, n);
  int s = 0;
  for (int i = lo; i < hi; ++i) s += hist[i];
  part[t] = s;
  __syncthreads();
  for (int d = 1; d < 1024; d <<= 1) {
    int v = (t >= d) ? part[t - d] : 0;
    __syncthreads();
    part[t] += v;
    __syncthreads();
  }
  int run = (t > 0) ? part[t - 1] : 0;
  for (int i = lo; i < hi; ++i) {
    row_ptr[i] = run;
    cursor[i] = run;
    run += hist[i];
  }
  if (t == 1023) row_ptr[n] = e;
}

__global__ void k_fill(const int* __restrict__ adj, int* __restrict__ cursor,
                       int* __restrict__ edge_src, int e) {
  int i = blockIdx.x * blockDim.x + threadIdx.x;
  if (i < e) {
    int s = adj[i], d = adj[e + i];
    int pos = atomicAdd(&cursor[d], 1);
    edge_src[pos] = s;
  }
}

// ---------------- gather (bf16), unroll-4 for MLP: agg[d] = mean of x[src]
__global__ __launch_bounds__(256) void k_gather(
    const short* __restrict__ x, const int* __restrict__ edge_src, const int* __restrict__ row_ptr,
    short* __restrict__ agg, int n) {
  const int wid = threadIdx.x >> 6;
  const int lane = threadIdx.x & 63;
  const int d = blockIdx.x * 4 + wid;
  if (d >= n) return;
  const int beg = row_ptr[d], end = row_ptr[d + 1];
  float4 acc = {0.f, 0.f, 0.f, 0.f};
  int i = beg;
  for (; i + 4 <= end; i += 4) {
    const int s0 = edge_src[i], s1 = edge_src[i + 1], s2 = edge_src[i + 2], s3 = edge_src[i + 3];
    const short4 v0 = *(const short4*)(x + (size_t)s0 * H + lane * 4);
    const short4 v1 = *(const short4*)(x + (size_t)s1 * H + lane * 4);
    const short4 v2 = *(const short4*)(x + (size_t)s2 * H + lane * 4);
    const short4 v3 = *(const short4*)(x + (size_t)s3 * H + lane * 4);
    acc.x += bf2f(v0.x) + bf2f(v1.x) + bf2f(v2.x) + bf2f(v3.x);
    acc.y += bf2f(v0.y) + bf2f(v1.y) + bf2f(v2.y) + bf2f(v3.y);
    acc.z += bf2f(v0.z) + bf2f(v1.z) + bf2f(v2.z) + bf2f(v3.z);
    acc.w += bf2f(v0.w) + bf2f(v1.w) + bf2f(v2.w) + bf2f(v3.w);
  }
  for (; i < end; ++i) {
    const int s = edge_src[i];
    const short4 v = *(const short4*)(x + (size_t)s * H + lane * 4);
    acc.x += bf2f(v.x); acc.y += bf2f(v.y); acc.z += bf2f(v.z); acc.w += bf2f(v.w);
  }
  const float inv = 1.f / fmaxf((float)(end - beg), 1.f);
  short4 o;
  o.x = bf16rne(acc.x * inv); o.y = bf16rne(acc.y * inv);
  o.z = bf16rne(acc.z * inv); o.w = bf16rne(acc.w * inv);
  *(short4*)(agg + (size_t)d * H + lane * 4) = o;
}

extern "C" void kernel_launch(void* const* d_in, const int* in_sizes, int n_in,
                              void* d_out, int out_size, void* d_ws, size_t ws_size,
                              hipStream_t stream) {
  const float* lit = (const float*)d_in[0];
  const float* cf = (const float*)d_in[1];
  const int* mask = (const int*)d_in[2];
  const int* adj = (const int*)d_in[3];
  const float* pe_w1 = (const float*)d_in[4];
  const float* pe_b1 = (const float*)d_in[5];
  const float* pe_w2 = (const float*)d_in[6];
  const float* pe_b2 = (const float*)d_in[7];
  const float* aiw = (const float*)d_in[8];
  const float* aib = (const float*)d_in[9];
  const float* aow = (const float*)d_in[10];
  const float* aob = (const float*)d_in[11];
  const float* attn_ln_g = (const float*)d_in[12];
  const float* attn_ln_b = (const float*)d_in[13];
  const float* gate_w = (const float*)d_in[14];
  const float* gate_b = (const float*)d_in[15];
  const float* trans_w = (const float*)d_in[16];
  const float* trans_b = (const float*)d_in[17];
  const float* fus_ln_g = (const float*)d_in[18];
  const float* fus_ln_b = (const float*)d_in[19];
  const float* mp_w = (const float*)d_in[20];
  const float* mp_b = (const float*)d_in[21];
  const float* mp_ln_g = (const float*)d_in[22];
  const float* mp_ln_b = (const float*)d_in[23];

  const int n = in_sizes[1] / FEAT;   // 20000
  const int e = in_sizes[3] / 2;      // 640000

  float* ws = (float*)d_ws;
  size_t off = 0;
  short* enc_bf16 = (short*)(ws + off); off += (size_t)n * 128;
  short* pm_bf16 = (short*)(ws + off); off += (size_t)n * 512;   // p then m (in-place)
  short* litmean_bf = (short*)(ws + off); off += (size_t)n * 128;
  short* x0_bf = (short*)(ws + off); off += (size_t)n * 128;
  short* x1_bf = (short*)(ws + off); off += (size_t)n * 128;
  short* agg_bf = (short*)(ws + off); off += (size_t)n * 128;
  int* flags = (int*)(ws + off); off += n;
  int* hist = (int*)(ws + off); off += n;
  int* row_ptr = (int*)(ws + off); off += n + 2;
  int* cursor = (int*)(ws + off); off += n;
  int* edge_src = (int*)(ws + off); off += e;
  short* w2P = (short*)(ws + off); off += 256 * 256 / 2;
  short* wqpP = (short*)(ws + off); off += 256 * 1024 / 2;
  short* wbigP = (short*)(ws + off); off += 1024 * 256 / 2;
  short* gwP = (short*)(ws + off); off += 512 * 256 / 2;
  short* twP = (short*)(ws + off); off += 512 * 256 / 2;
  short* mp0P = (short*)(ws + off); off += 512 * 256 / 2;
  short* mp1P = (short*)(ws + off); off += 512 * 256 / 2;
  float* bias_p = ws + off; off += 1024;
  float* bias_out = ws + off; off += 256;

  dim3 blk(256);
  // weight prep
  k_pack_w<<<32, blk, 0, stream>>>(pe_w2, w2P, 256, 256);
  k_pack_w4<<<dim3(64, 4), blk, 0, stream>>>(gate_w, trans_w, mp_w, mp_w + 512 * 256,
                                             gwP, twP, mp0P, mp1P);
  k_make_wqp<<<128, blk, 0, stream>>>(aiw, wqpP);
  k_make_wbig<<<128, blk, 0, stream>>>(aiw, aow, wbigP);
  k_bias_p<<<4, blk, 0, stream>>>(aiw, aib, bias_p);
  k_bias_out<<<1, blk, 0, stream>>>(aow, aib, aob, bias_out);

  k_enc_mfma<<<n / 32, blk, 0, stream>>>(cf, pe_w1, pe_b1, w2P, pe_b2, wqpP, bias_p, enc_bf16, pm_bf16, n);
  k_attn<<<n, blk, 0, stream>>>(lit, mask, pm_bf16, pm_bf16, litmean_bf, flags, n);

  // CSR build
  k_zero_int<<<(n + 255) / 256, blk, 0, stream>>>(hist, n);
  k_hist<<<(e + 255) / 256, blk, 0, stream>>>(adj + e, hist, e);
  k_scan<<<1, 1024, 0, stream>>>(hist, row_ptr, cursor, n, e);
  k_fill<<<(e + 255) / 256, blk, 0, stream>>>(adj, cursor, edge_src, e);

  k_fused<<<n / 32, blk, 0, stream>>>(pm_bf16, wbigP, bias_out, enc_bf16, litmean_bf, flags,
                                      attn_ln_g, attn_ln_b, gwP, twP, gate_b, trans_b,
                                      fus_ln_g, fus_ln_b, x0_bf, n);
  // layer 0
  k_gather<<<(n + 3) / 4, blk, 0, stream>>>(x0_bf, edge_src, row_ptr, agg_bf, n);
  k_mp_mfma<<<n / 32, blk, 0, stream>>>(x0_bf, agg_bf, mp0P, mp_b, mp_ln_g, mp_ln_b,
                                        nullptr, x1_bf, n);
  // layer 1
  k_gather<<<(n + 3) / 4, blk, 0, stream>>>(x1_bf, edge_src, row_ptr, agg_bf, n);
  k_mp_mfma<<<n / 32, blk, 0, stream>>>(x1_bf, agg_bf, mp1P, mp_b + 256, mp_ln_g + 256, mp_ln_b + 256,
                                        (float*)d_out, nullptr, n);
}